// Round 2
// baseline (387.957 us; speedup 1.0000x reference)
//
#include <hip/hip_runtime.h>

typedef short bf16x8 __attribute__((ext_vector_type(8)));
typedef float f32x4 __attribute__((ext_vector_type(4)));
typedef unsigned short u16;
typedef unsigned short u16x4 __attribute__((ext_vector_type(4)));
typedef unsigned short u16x8 __attribute__((ext_vector_type(8)));

#define NB 4
#define LEN 1024
#define DM 1024
#define NH 16
#define HD 64

__device__ __forceinline__ u16 f2bf(float f) {
    union { float f; unsigned u; } v; v.f = f;
    return (u16)((v.u + 0x7fffu + ((v.u >> 16) & 1u)) >> 16);
}

__device__ __forceinline__ f32x4 mfma16(bf16x8 a, bf16x8 b, f32x4 c) {
    return __builtin_amdgcn_mfma_f32_16x16x32_bf16(a, b, c, 0, 0, 0);
}

// ---------------- cast fp32 -> bf16 (vectorized) ----------------
__global__ void cast_f32_bf16(const float* __restrict__ in, u16* __restrict__ out, int n4) {
    int i = blockIdx.x * blockDim.x + threadIdx.x;
    if (i < n4) {
        float4 v = ((const float4*)in)[i];
        u16x4 o;
        o[0] = f2bf(v.x); o[1] = f2bf(v.y); o[2] = f2bf(v.z); o[3] = f2bf(v.w);
        ((u16x4*)out)[i] = o;
    }
}

// ---------------- transpose + cast weights: W[K][N] -> WT[N][K] bf16 ----------------
__global__ void transpose_cast(const float* __restrict__ W, u16* __restrict__ WT, int K, int N) {
    __shared__ float tile[32][33];
    int n0 = blockIdx.x * 32, k0 = blockIdx.y * 32;
    int tx = threadIdx.x, ty = threadIdx.y;
    #pragma unroll
    for (int j = 0; j < 4; j++) {
        int r = ty + j * 8;
        tile[r][tx] = W[(size_t)(k0 + r) * N + n0 + tx];
    }
    __syncthreads();
    #pragma unroll
    for (int j = 0; j < 4; j++) {
        int r = ty + j * 8;  // local n
        WT[(size_t)(n0 + r) * K + k0 + tx] = f2bf(tile[tx][r]);
    }
}

// ---------------- r = pos_embed @ Wr  (2048x64 @ 64x64) -> bf16 ----------------
__global__ void r_proj(const float* __restrict__ pos, const float* __restrict__ Wr,
                       u16* __restrict__ rbf) {
    int idx = blockIdx.x * 256 + threadIdx.x;  // 2048*64 = 131072
    int row = idx >> 6, col = idx & 63;
    float s = 0.f;
    #pragma unroll
    for (int kk = 0; kk < 64; kk++) s += pos[row * 64 + kk] * Wr[kk * 64 + col];
    rbf[idx] = f2bf(s);
}

// ---------------- projection GEMM: C = A(bf16 MxK) @ WT^T, fused epilogues ----------------
__global__ __launch_bounds__(256) void gemm_proj(
    const u16* __restrict__ Abf, const u16* __restrict__ BT,
    const float* __restrict__ rrb, const float* __restrict__ rwb,
    u16* __restrict__ out1, u16* __restrict__ out2, int mode)
{
    const int K = 1024;
    const int n0 = blockIdx.x * 64;
    const int m0 = blockIdx.y * 128;
    const int tid = threadIdx.x;
    const int w = tid >> 6, lane = tid & 63, g = lane >> 4, c = lane & 15;
    const int wr = m0 + w * 32;

    const f32x4 fzero = {0.f, 0.f, 0.f, 0.f};
    f32x4 acc[2][4];
    #pragma unroll
    for (int rt = 0; rt < 2; rt++) {
        #pragma unroll
        for (int ct = 0; ct < 4; ct++) acc[rt][ct] = fzero;
    }

    const u16* aptr0 = Abf + (size_t)(wr + c) * K + g * 8;
    const u16* aptr1 = Abf + (size_t)(wr + 16 + c) * K + g * 8;
    const u16* bptr0 = BT + (size_t)(n0 + c) * K + g * 8;
    const u16* bptr1 = BT + (size_t)(n0 + 16 + c) * K + g * 8;
    const u16* bptr2 = BT + (size_t)(n0 + 32 + c) * K + g * 8;
    const u16* bptr3 = BT + (size_t)(n0 + 48 + c) * K + g * 8;

    #pragma unroll 2
    for (int ks = 0; ks < 32; ks++) {
        const int off = ks * 32;
        bf16x8 a0 = *(const bf16x8*)(aptr0 + off);
        bf16x8 a1 = *(const bf16x8*)(aptr1 + off);
        bf16x8 b0 = *(const bf16x8*)(bptr0 + off);
        bf16x8 b1 = *(const bf16x8*)(bptr1 + off);
        bf16x8 b2 = *(const bf16x8*)(bptr2 + off);
        bf16x8 b3 = *(const bf16x8*)(bptr3 + off);
        acc[0][0] = mfma16(a0, b0, acc[0][0]);
        acc[1][0] = mfma16(a1, b0, acc[1][0]);
        acc[0][1] = mfma16(a0, b1, acc[0][1]);
        acc[1][1] = mfma16(a1, b1, acc[1][1]);
        acc[0][2] = mfma16(a0, b2, acc[0][2]);
        acc[1][2] = mfma16(a1, b2, acc[1][2]);
        acc[0][3] = mfma16(a0, b3, acc[0][3]);
        acc[1][3] = mfma16(a1, b3, acc[1][3]);
    }

    #pragma unroll
    for (int ct = 0; ct < 4; ct++) {
        const int n = n0 + ct * 16 + c;
        float b1v = 0.f, b2v = 0.f;
        if (mode == 0) { b1v = rrb[n]; b2v = rwb[n]; }
        #pragma unroll
        for (int rt = 0; rt < 2; rt++) {
            #pragma unroll
            for (int r = 0; r < 4; r++) {
                const int row = wr + rt * 16 + g * 4 + r;
                const int bb = row >> 10, l = row & 1023;
                const float v = acc[rt][ct][r];
                if (mode == 0) {
                    size_t idx = (((size_t)(bb * NH + (n >> 6))) * LEN + l) * HD + (n & 63);
                    out1[idx] = f2bf((v + b1v) * 0.125f);
                    out2[idx] = f2bf((v + b2v) * 0.125f);
                } else if (n < DM) {
                    size_t idx = (((size_t)(bb * NH + (n >> 6))) * LEN + l) * HD + (n & 63);
                    out1[idx] = f2bf(v);
                } else {
                    size_t idx = (((size_t)(bb * NH + ((n - DM) >> 6))) * LEN + l) * HD + (n & 63);
                    out2[idx] = f2bf(v);
                }
            }
        }
    }
}

// ---------------- vhs[b,h,l,d] -> vhsT[b,h,d,l] ----------------
__global__ void transpose_v(const u16* __restrict__ vhs, u16* __restrict__ vhsT) {
    __shared__ u16 tile[64][72];
    const int bhead = blockIdx.y;
    const int l0 = blockIdx.x * 64;
    const int tid = threadIdx.x;
    #pragma unroll
    for (int i = 0; i < 2; i++) {
        int idx = i * 256 + tid;
        int row = idx >> 3;
        int cg = (idx & 7) * 8;
        u16x8 v = *(const u16x8*)(vhs + ((size_t)bhead * LEN + l0 + row) * HD + cg);
        *(u16x8*)&tile[row][cg] = v;
    }
    __syncthreads();
    #pragma unroll
    for (int i = 0; i < 2; i++) {
        int idx = i * 256 + tid;
        int d = idx >> 3;
        int lg = (idx & 7) * 8;
        u16x8 o;
        #pragma unroll
        for (int j = 0; j < 8; j++) o[j] = tile[lg + j][d];
        *(u16x8*)(vhsT + ((size_t)bhead * HD + d) * LEN + l0 + lg) = o;
    }
}

// ---------------- fused rel-attention, v2 ----------------
// grid: (L/64, B*H), 256 threads = 4 waves, each wave owns 16 q-rows.
// KVBLK = 64. All LDS is wave-local: NO __syncthreads anywhere.
__global__ __launch_bounds__(256) void attn_kernel(
    const u16* __restrict__ A1, const u16* __restrict__ A2,
    const u16* __restrict__ khs, const u16* __restrict__ vhsT,
    const u16* __restrict__ rbf, const int* __restrict__ mask,
    float* __restrict__ outp)
{
    // G^T band scores: [m 0..79][q 0..15], stride 20 dwords (f32x4-addressed)
    __shared__ f32x4 GlT4[4][80][5];
    // P tile bf16: [q 0..15][k 0..63], stride 72 u16 (144 B, 16B-aligned rows)
    __shared__ u16 Pl[4][16][72];

    const int bh = blockIdx.y;
    const int b = bh >> 4, h = bh & 15;
    const int tid = threadIdx.x;
    const int w = tid >> 6, lane = tid & 63, g = lane >> 4, c = lane & 15;
    const int q0 = blockIdx.x * 64 + w * 16;

    const u16* A1p = A1 + ((size_t)bh * LEN + q0) * HD;
    const u16* A2p = A2 + ((size_t)bh * LEN + q0) * HD;
    const u16* Kp = khs + (size_t)bh * LEN * HD;
    const u16* Vp = vhsT + (size_t)bh * HD * LEN;
    const int* mp = mask + b * LEN;

    float* glw = (float*)&GlT4[w][0][0];

    // A-fragments: row = c (q), k = kf*32 + 8g + e
    bf16x8 a1f[2], a2f[2];
    #pragma unroll
    for (int kf = 0; kf < 2; kf++) {
        a1f[kf] = *(const bf16x8*)(A1p + c * HD + kf * 32 + g * 8);
        a2f[kf] = *(const bf16x8*)(A2p + c * HD + kf * 32 + g * 8);
    }

    const f32x4 fzero = {0.f, 0.f, 0.f, 0.f};
    float mrow[4], lrow[4];
    f32x4 oacc[4];
    #pragma unroll
    for (int r = 0; r < 4; r++) { mrow[r] = -3.0e38f; lrow[r] = 0.f; }
    #pragma unroll
    for (int dt = 0; dt < 4; dt++) oacc[dt] = fzero;

    for (int kt = 0; kt < 16; kt++) {
        const int c0 = kt * 64;

        // ---- AC = A1 . K^T : S tile 16 q x 64 k ----
        f32x4 s[4];
        #pragma unroll
        for (int ct = 0; ct < 4; ct++) s[ct] = fzero;
        #pragma unroll
        for (int ct = 0; ct < 4; ct++) {
            #pragma unroll
            for (int kf = 0; kf < 2; kf++) {
                bf16x8 bk = *(const bf16x8*)(Kp + (size_t)(c0 + ct * 16 + c) * HD + kf * 32 + g * 8);
                s[ct] = mfma16(a1f[kf], bk, s[ct]);
            }
        }

        // ---- band G[q, m] = A2[q] . r[base+m], m in [0,79); BD[q,k] = G[q][k+15-q] ----
        const int base = LEN + c0 - q0 - 15;
        #pragma unroll
        for (int gt = 0; gt < 5; gt++) {
            f32x4 gacc = fzero;
            #pragma unroll
            for (int kf = 0; kf < 2; kf++) {
                bf16x8 br = *(const bf16x8*)(rbf + (size_t)(base + gt * 16 + c) * HD + kf * 32 + g * 8);
                gacc = mfma16(a2f[kf], br, gacc);
            }
            // store transposed: G^T[m = gt*16+c][q = 4g..4g+3]
            GlT4[w][gt * 16 + c][g] = gacc;
        }

        // ---- gather BD + key mask ----
        #pragma unroll
        for (int ct = 0; ct < 4; ct++) {
            const int mv = mp[c0 + ct * 16 + c];
            #pragma unroll
            for (int r = 0; r < 4; r++) {
                const int qw = g * 4 + r;
                const int m = ct * 16 + c + 15 - qw;
                float val = s[ct][r] + glw[m * 20 + qw];
                s[ct][r] = mv ? val : -3.0e38f;
            }
        }

        // ---- online softmax (max-reduce only; sum stays per-lane partial) ----
        #pragma unroll
        for (int r = 0; r < 4; r++) {
            float t = fmaxf(fmaxf(s[0][r], s[1][r]), fmaxf(s[2][r], s[3][r]));
            #pragma unroll
            for (int off = 1; off < 16; off <<= 1) t = fmaxf(t, __shfl_xor(t, off, 16));
            const float mold = mrow[r];
            const float mnew = fmaxf(mold, t);
            const float alpha = __expf(mold - mnew);
            mrow[r] = mnew;
            float ps = 0.f;
            #pragma unroll
            for (int ct = 0; ct < 4; ct++) {
                float p = __expf(s[ct][r] - mnew);
                s[ct][r] = p;
                ps += p;
            }
            lrow[r] = lrow[r] * alpha + ps;
            #pragma unroll
            for (int dt = 0; dt < 4; dt++) oacc[dt][r] *= alpha;
        }

        // ---- P -> LDS (bf16): Pl[q][k] ----
        #pragma unroll
        for (int ct = 0; ct < 4; ct++) {
            #pragma unroll
            for (int r = 0; r < 4; r++)
                Pl[w][g * 4 + r][ct * 16 + c] = f2bf(s[ct][r]);
        }

        // ---- PV: O += P @ V^T ----
        bf16x8 pa[2];
        #pragma unroll
        for (int kf = 0; kf < 2; kf++)
            pa[kf] = *(const bf16x8*)&Pl[w][c][kf * 32 + g * 8];
        #pragma unroll
        for (int dt = 0; dt < 4; dt++) {
            #pragma unroll
            for (int kf = 0; kf < 2; kf++) {
                bf16x8 bv = *(const bf16x8*)(Vp + (size_t)(dt * 16 + c) * LEN + c0 + kf * 32 + g * 8);
                oacc[dt] = mfma16(pa[kf], bv, oacc[dt]);
            }
        }
    }

    // ---- epilogue: reduce row-sums across 16 lanes, normalize, store ----
    #pragma unroll
    for (int r = 0; r < 4; r++) {
        float sum = lrow[r];
        #pragma unroll
        for (int off = 1; off < 16; off <<= 1) sum += __shfl_xor(sum, off, 16);
        const float inv = sum > 0.f ? 1.0f / sum : 0.f;
        const int l = q0 + g * 4 + r;
        #pragma unroll
        for (int dt = 0; dt < 4; dt++) {
            outp[((size_t)b * LEN + l) * DM + h * HD + dt * 16 + c] = oacc[dt][r] * inv;
        }
    }
}

extern "C" void kernel_launch(void* const* d_in, const int* in_sizes, int n_in,
                              void* d_out, int out_size, void* d_ws, size_t ws_size,
                              hipStream_t stream) {
    const float* q   = (const float*)d_in[0];
    const float* k   = (const float*)d_in[1];
    const int*   msk = (const int*)d_in[2];
    const float* pos = (const float*)d_in[3];
    const float* Wq  = (const float*)d_in[4];
    const float* Wkv = (const float*)d_in[5];
    const float* Wr  = (const float*)d_in[6];
    const float* rrb = (const float*)d_in[7];
    const float* rwb = (const float*)d_in[8];
    float* outp = (float*)d_out;
    char* ws = (char*)d_ws;

    u16* qbf  = (u16*)(ws + 0);              // 8 MB
    u16* kbf  = (u16*)(ws + 8388608);        // 8 MB
    u16* WqT  = (u16*)(ws + 16777216);       // 2 MB
    u16* WkvT = (u16*)(ws + 18874368);       // 4 MB
    u16* rbf  = (u16*)(ws + 23068672);       // 2064*64*2 (16 pad rows, never gathered)
    u16* A1   = (u16*)(ws + 23332864);       // 8 MB
    u16* A2   = (u16*)(ws + 31721472);       // 8 MB
    u16* khs  = (u16*)(ws + 40110080);       // 8 MB
    u16* vhs  = (u16*)(ws + 48498688);       // 8 MB
    u16* vhsT = (u16*)(ws + 56887296);       // 8 MB  (end: 65275904)

    cast_f32_bf16<<<4096, 256, 0, stream>>>(q, qbf, 1048576);
    cast_f32_bf16<<<4096, 256, 0, stream>>>(k, kbf, 1048576);
    transpose_cast<<<dim3(32, 32), dim3(32, 8), 0, stream>>>(Wq, WqT, 1024, 1024);
    transpose_cast<<<dim3(64, 32), dim3(32, 8), 0, stream>>>(Wkv, WkvT, 1024, 2048);
    r_proj<<<512, 256, 0, stream>>>(pos, Wr, rbf);
    gemm_proj<<<dim3(16, 32), 256, 0, stream>>>(qbf, WqT, rrb, rwb, A1, A2, 0);
    gemm_proj<<<dim3(32, 32), 256, 0, stream>>>(kbf, WkvT, nullptr, nullptr, khs, vhs, 1);
    transpose_v<<<dim3(16, 64), 256, 0, stream>>>(vhs, vhsT);
    attn_kernel<<<dim3(16, 64), 256, 0, stream>>>(A1, A2, khs, vhsT, rbf, msk, outp);
}

// Round 3
// 379.890 us; speedup vs baseline: 1.0212x; 1.0212x over previous
//
#include <hip/hip_runtime.h>

typedef short bf16x8 __attribute__((ext_vector_type(8)));
typedef float f32x4 __attribute__((ext_vector_type(4)));
typedef unsigned short u16;
typedef unsigned short u16x4 __attribute__((ext_vector_type(4)));
typedef unsigned short u16x8 __attribute__((ext_vector_type(8)));

#define NB 4
#define LEN 1024
#define DM 1024
#define NH 16
#define HD 64

__device__ __forceinline__ u16 f2bf(float f) {
    union { float f; unsigned u; } v; v.f = f;
    return (u16)((v.u + 0x7fffu + ((v.u >> 16) & 1u)) >> 16);
}

__device__ __forceinline__ f32x4 mfma16(bf16x8 a, bf16x8 b, f32x4 c) {
    return __builtin_amdgcn_mfma_f32_16x16x32_bf16(a, b, c, 0, 0, 0);
}

// ---------------- cast fp32 -> bf16 (vectorized) ----------------
__global__ void cast_f32_bf16(const float* __restrict__ in, u16* __restrict__ out, int n4) {
    int i = blockIdx.x * blockDim.x + threadIdx.x;
    if (i < n4) {
        float4 v = ((const float4*)in)[i];
        u16x4 o;
        o[0] = f2bf(v.x); o[1] = f2bf(v.y); o[2] = f2bf(v.z); o[3] = f2bf(v.w);
        ((u16x4*)out)[i] = o;
    }
}

// ---------------- mask -> additive bias ----------------
__global__ void mask_bias(const int* __restrict__ mask, float* __restrict__ mb, int n) {
    int i = blockIdx.x * 256 + threadIdx.x;
    if (i < n) mb[i] = mask[i] ? 0.f : -3.0e38f;
}

// ---------------- transpose + cast weights: W[K][N] -> WT[N][K] bf16 ----------------
__global__ void transpose_cast(const float* __restrict__ W, u16* __restrict__ WT, int K, int N) {
    __shared__ float tile[32][33];
    int n0 = blockIdx.x * 32, k0 = blockIdx.y * 32;
    int tx = threadIdx.x, ty = threadIdx.y;
    #pragma unroll
    for (int j = 0; j < 4; j++) {
        int r = ty + j * 8;
        tile[r][tx] = W[(size_t)(k0 + r) * N + n0 + tx];
    }
    __syncthreads();
    #pragma unroll
    for (int j = 0; j < 4; j++) {
        int r = ty + j * 8;  // local n
        WT[(size_t)(n0 + r) * K + k0 + tx] = f2bf(tile[tx][r]);
    }
}

// ---------------- r = pos_embed @ Wr  (2048x64 @ 64x64) -> bf16 ----------------
__global__ void r_proj(const float* __restrict__ pos, const float* __restrict__ Wr,
                       u16* __restrict__ rbf) {
    int idx = blockIdx.x * 256 + threadIdx.x;  // 2048*64 = 131072
    int row = idx >> 6, col = idx & 63;
    float s = 0.f;
    #pragma unroll
    for (int kk = 0; kk < 64; kk++) s += pos[row * 64 + kk] * Wr[kk * 64 + col];
    rbf[idx] = f2bf(s);
}

// ---------------- projection GEMM: C = A(bf16 MxK) @ WT^T, fused epilogues ----------------
__global__ __launch_bounds__(256) void gemm_proj(
    const u16* __restrict__ Abf, const u16* __restrict__ BT,
    const float* __restrict__ rrb, const float* __restrict__ rwb,
    u16* __restrict__ out1, u16* __restrict__ out2, int mode)
{
    const int K = 1024;
    const int n0 = blockIdx.x * 64;
    const int m0 = blockIdx.y * 128;
    const int tid = threadIdx.x;
    const int w = tid >> 6, lane = tid & 63, g = lane >> 4, c = lane & 15;
    const int wr = m0 + w * 32;

    const f32x4 fzero = {0.f, 0.f, 0.f, 0.f};
    f32x4 acc[2][4];
    #pragma unroll
    for (int rt = 0; rt < 2; rt++) {
        #pragma unroll
        for (int ct = 0; ct < 4; ct++) acc[rt][ct] = fzero;
    }

    const u16* aptr0 = Abf + (size_t)(wr + c) * K + g * 8;
    const u16* aptr1 = Abf + (size_t)(wr + 16 + c) * K + g * 8;
    const u16* bptr0 = BT + (size_t)(n0 + c) * K + g * 8;
    const u16* bptr1 = BT + (size_t)(n0 + 16 + c) * K + g * 8;
    const u16* bptr2 = BT + (size_t)(n0 + 32 + c) * K + g * 8;
    const u16* bptr3 = BT + (size_t)(n0 + 48 + c) * K + g * 8;

    #pragma unroll 2
    for (int ks = 0; ks < 32; ks++) {
        const int off = ks * 32;
        bf16x8 a0 = *(const bf16x8*)(aptr0 + off);
        bf16x8 a1 = *(const bf16x8*)(aptr1 + off);
        bf16x8 b0 = *(const bf16x8*)(bptr0 + off);
        bf16x8 b1 = *(const bf16x8*)(bptr1 + off);
        bf16x8 b2 = *(const bf16x8*)(bptr2 + off);
        bf16x8 b3 = *(const bf16x8*)(bptr3 + off);
        acc[0][0] = mfma16(a0, b0, acc[0][0]);
        acc[1][0] = mfma16(a1, b0, acc[1][0]);
        acc[0][1] = mfma16(a0, b1, acc[0][1]);
        acc[1][1] = mfma16(a1, b1, acc[1][1]);
        acc[0][2] = mfma16(a0, b2, acc[0][2]);
        acc[1][2] = mfma16(a1, b2, acc[1][2]);
        acc[0][3] = mfma16(a0, b3, acc[0][3]);
        acc[1][3] = mfma16(a1, b3, acc[1][3]);
    }

    #pragma unroll
    for (int ct = 0; ct < 4; ct++) {
        const int n = n0 + ct * 16 + c;
        float b1v = 0.f, b2v = 0.f;
        if (mode == 0) { b1v = rrb[n]; b2v = rwb[n]; }
        #pragma unroll
        for (int rt = 0; rt < 2; rt++) {
            #pragma unroll
            for (int r = 0; r < 4; r++) {
                const int row = wr + rt * 16 + g * 4 + r;
                const int bb = row >> 10, l = row & 1023;
                const float v = acc[rt][ct][r];
                if (mode == 0) {
                    size_t idx = (((size_t)(bb * NH + (n >> 6))) * LEN + l) * HD + (n & 63);
                    out1[idx] = f2bf((v + b1v) * 0.125f);
                    out2[idx] = f2bf((v + b2v) * 0.125f);
                } else if (n < DM) {
                    size_t idx = (((size_t)(bb * NH + (n >> 6))) * LEN + l) * HD + (n & 63);
                    out1[idx] = f2bf(v);
                } else {
                    size_t idx = (((size_t)(bb * NH + ((n - DM) >> 6))) * LEN + l) * HD + (n & 63);
                    out2[idx] = f2bf(v);
                }
            }
        }
    }
}

// ---------------- vhs[b,h,l,d] -> vhsT[b,h,d,l] ----------------
__global__ void transpose_v(const u16* __restrict__ vhs, u16* __restrict__ vhsT) {
    __shared__ u16 tile[64][72];
    const int bhead = blockIdx.y;
    const int l0 = blockIdx.x * 64;
    const int tid = threadIdx.x;
    #pragma unroll
    for (int i = 0; i < 2; i++) {
        int idx = i * 256 + tid;
        int row = idx >> 3;
        int cg = (idx & 7) * 8;
        u16x8 v = *(const u16x8*)(vhs + ((size_t)bhead * LEN + l0 + row) * HD + cg);
        *(u16x8*)&tile[row][cg] = v;
    }
    __syncthreads();
    #pragma unroll
    for (int i = 0; i < 2; i++) {
        int idx = i * 256 + tid;
        int d = idx >> 3;
        int lg = (idx & 7) * 8;
        u16x8 o;
        #pragma unroll
        for (int j = 0; j < 8; j++) o[j] = tile[lg + j][d];
        *(u16x8*)(vhsT + ((size_t)bhead * HD + d) * LEN + l0 + lg) = o;
    }
}

// ---------------- fused rel-attention, v3: S^T orientation + SW pipeline ----------------
// grid: (L/64, B*H), 4 waves/block, wave owns 16 q-rows (q = lane&15), KVBLK=32.
// Wave-local LDS, zero barriers. Register-prefetched K/rbf/bias one tile ahead.
__global__ __launch_bounds__(256, 3) void attn_kernel(
    const u16* __restrict__ A1, const u16* __restrict__ A2,
    const u16* __restrict__ khs, const u16* __restrict__ vhsT,
    const u16* __restrict__ rbf, const float* __restrict__ mbias,
    float* __restrict__ outp)
{
    __shared__ f32x4 Gl4[4][16][12];   // G[q][m] rows, stride 48 dwords
    __shared__ u16 Pl[4][16][40];      // P[q][k] rows, stride 40 u16

    const int bh = blockIdx.y;
    const int b = bh >> 4, h = bh & 15;
    const int tid = threadIdx.x;
    const int w = tid >> 6, lane = tid & 63, g = lane >> 4, c = lane & 15;
    const int q0 = blockIdx.x * 64 + w * 16;

    const u16* A1p = A1 + ((size_t)bh * LEN + q0) * HD;
    const u16* A2p = A2 + ((size_t)bh * LEN + q0) * HD;
    const u16* Kp  = khs + (size_t)bh * LEN * HD;
    const u16* Vp  = vhsT + (size_t)bh * HD * LEN;
    const float* bp = mbias + b * LEN;
    float* glw = (float*)&Gl4[w][0][0];
    u16* plw = &Pl[w][0][0];

    // q-side fragments (B-operands): lane c holds row q0+c
    bf16x8 a1f[2], a2f[2];
    #pragma unroll
    for (int kf = 0; kf < 2; kf++) {
        a1f[kf] = *(const bf16x8*)(A1p + c * HD + kf * 32 + g * 8);
        a2f[kf] = *(const bf16x8*)(A2p + c * HD + kf * 32 + g * 8);
    }

    const f32x4 fzero = {0.f, 0.f, 0.f, 0.f};
    f32x4 oacc[4];
    #pragma unroll
    for (int dt = 0; dt < 4; dt++) oacc[dt] = fzero;
    float mrow = -3.0e38f, lrow = 0.f;
    f32x4 s[2];

    bf16x8 Kb[2][2];   // K rows (A-operand)  [ct][kf]
    bf16x8 Rb[3][2];   // rbf rows (A-operand) [gt][kf]
    bf16x8 Vb[4];      // V^T rows (A-operand) [dt]
    f32x4  Bb[2];      // mask bias [ct]

    auto LOADS = [&](int KT) {
        const int c0_ = KT * 32;
        const int bm_ = LEN + c0_ - q0 - 15;
        #pragma unroll
        for (int ct = 0; ct < 2; ct++)
            #pragma unroll
            for (int kf = 0; kf < 2; kf++)
                Kb[ct][kf] = *(const bf16x8*)(Kp + (size_t)(c0_ + ct * 16 + c) * HD + kf * 32 + g * 8);
        #pragma unroll
        for (int gt = 0; gt < 3; gt++)
            #pragma unroll
            for (int kf = 0; kf < 2; kf++)
                Rb[gt][kf] = *(const bf16x8*)(rbf + (size_t)(bm_ + gt * 16 + c) * HD + kf * 32 + g * 8);
        #pragma unroll
        for (int ct = 0; ct < 2; ct++)
            Bb[ct] = *(const f32x4*)(bp + c0_ + ct * 16 + 4 * g);
    };

    auto VLOADS = [&](int KT) {
        const int c0_ = KT * 32;
        #pragma unroll
        for (int dt = 0; dt < 4; dt++)
            Vb[dt] = *(const bf16x8*)(Vp + (size_t)(dt * 16 + c) * LEN + c0_ + g * 8);
    };

    // S^T tile: per-lane q = c, k = ct*16 + 4g + r. Scores -> s[ct][r].
    auto PHASE_B = [&]() {
        f32x4 sc0 = fzero, sc1 = fzero;
        sc0 = mfma16(Kb[0][0], a1f[0], sc0);
        sc0 = mfma16(Kb[0][1], a1f[1], sc0);
        sc1 = mfma16(Kb[1][0], a1f[0], sc1);
        sc1 = mfma16(Kb[1][1], a1f[1], sc1);
        #pragma unroll
        for (int gt = 0; gt < 3; gt++) {
            f32x4 ga = fzero;
            ga = mfma16(Rb[gt][0], a2f[0], ga);
            ga = mfma16(Rb[gt][1], a2f[1], ga);
            Gl4[w][c][gt * 4 + g] = ga;   // G[q=c][m=gt*16+4g..+3]
        }
        // gather band: BD[q=c][k] = G[c][k + 15 - c]
        #pragma unroll
        for (int r = 0; r < 4; r++) {
            const int base = 47 * c + 4 * g + r + 15;
            s[0][r] = sc0[r] + glw[base] + Bb[0][r];
            s[1][r] = sc1[r] + glw[base + 16] + Bb[1][r];
        }
    };

    auto ACOMP = [&]() {
        float t = fmaxf(fmaxf(fmaxf(s[0][0], s[0][1]), fmaxf(s[0][2], s[0][3])),
                        fmaxf(fmaxf(s[1][0], s[1][1]), fmaxf(s[1][2], s[1][3])));
        t = fmaxf(t, __shfl_xor(t, 16));
        t = fmaxf(t, __shfl_xor(t, 32));
        const float mnew = fmaxf(mrow, t);
        const float alpha = __expf(mrow - mnew);
        mrow = mnew;
        float ps = 0.f;
        u16x4 pk0, pk1;
        #pragma unroll
        for (int r = 0; r < 4; r++) {
            float p0 = __expf(s[0][r] - mnew);
            float p1 = __expf(s[1][r] - mnew);
            ps += p0 + p1;
            pk0[r] = f2bf(p0);
            pk1[r] = f2bf(p1);
        }
        lrow = lrow * alpha + ps;
        #pragma unroll
        for (int dt = 0; dt < 4; dt++)
            #pragma unroll
            for (int r = 0; r < 4; r++) oacc[dt][r] *= alpha;
        *(u16x4*)&plw[c * 40 + 4 * g] = pk0;
        *(u16x4*)&plw[c * 40 + 16 + 4 * g] = pk1;
        bf16x8 pb = *(const bf16x8*)&plw[c * 40 + g * 8];
        #pragma unroll
        for (int dt = 0; dt < 4; dt++)
            oacc[dt] = mfma16(Vb[dt], pb, oacc[dt]);
    };

    // ---- software pipeline ----
    LOADS(0);
    PHASE_B();
    for (int kt = 1; kt < 32; kt++) {
        VLOADS(kt - 1);      // V for the tile being finished
        LOADS(kt);           // K/rbf/bias for the tile about to start
        ACOMP();             // softmax + P + PV for tile kt-1 (hides loads)
        PHASE_B();           // scores for tile kt
    }
    VLOADS(31);
    ACOMP();

    // ---- epilogue ----
    float sum = lrow;
    sum += __shfl_xor(sum, 16);
    sum += __shfl_xor(sum, 32);
    const float inv = sum > 0.f ? 1.0f / sum : 0.f;
    const int l = q0 + c;
    float* op = outp + ((size_t)b * LEN + l) * DM + h * HD;
    #pragma unroll
    for (int dt = 0; dt < 4; dt++) {
        f32x4 o;
        #pragma unroll
        for (int r = 0; r < 4; r++) o[r] = oacc[dt][r] * inv;
        *(f32x4*)(op + dt * 16 + 4 * g) = o;
    }
}

extern "C" void kernel_launch(void* const* d_in, const int* in_sizes, int n_in,
                              void* d_out, int out_size, void* d_ws, size_t ws_size,
                              hipStream_t stream) {
    const float* q   = (const float*)d_in[0];
    const float* k   = (const float*)d_in[1];
    const int*   msk = (const int*)d_in[2];
    const float* pos = (const float*)d_in[3];
    const float* Wq  = (const float*)d_in[4];
    const float* Wkv = (const float*)d_in[5];
    const float* Wr  = (const float*)d_in[6];
    const float* rrb = (const float*)d_in[7];
    const float* rwb = (const float*)d_in[8];
    float* outp = (float*)d_out;
    char* ws = (char*)d_ws;

    u16* qbf  = (u16*)(ws + 0);              // 8 MB
    u16* kbf  = (u16*)(ws + 8388608);        // 8 MB
    u16* WqT  = (u16*)(ws + 16777216);       // 2 MB
    u16* WkvT = (u16*)(ws + 18874368);       // 4 MB
    u16* rbf  = (u16*)(ws + 23068672);       // 2064*64*2 (16 pad rows, never gathered)
    u16* A1   = (u16*)(ws + 23332864);       // 8 MB
    u16* A2   = (u16*)(ws + 31721472);       // 8 MB
    u16* khs  = (u16*)(ws + 40110080);       // 8 MB
    u16* vhs  = (u16*)(ws + 48498688);       // 8 MB
    u16* vhsT = (u16*)(ws + 56887296);       // 8 MB  (end: 65275904)
    float* mb = (float*)(ws + 65275904);     // 16 KB mask bias

    cast_f32_bf16<<<4096, 256, 0, stream>>>(q, qbf, 1048576);
    cast_f32_bf16<<<4096, 256, 0, stream>>>(k, kbf, 1048576);
    mask_bias<<<16, 256, 0, stream>>>(msk, mb, NB * LEN);
    transpose_cast<<<dim3(32, 32), dim3(32, 8), 0, stream>>>(Wq, WqT, 1024, 1024);
    transpose_cast<<<dim3(64, 32), dim3(32, 8), 0, stream>>>(Wkv, WkvT, 1024, 2048);
    r_proj<<<512, 256, 0, stream>>>(pos, Wr, rbf);
    gemm_proj<<<dim3(16, 32), 256, 0, stream>>>(qbf, WqT, rrb, rwb, A1, A2, 0);
    gemm_proj<<<dim3(32, 32), 256, 0, stream>>>(kbf, WkvT, nullptr, nullptr, khs, vhs, 1);
    transpose_v<<<dim3(16, 64), 256, 0, stream>>>(vhs, vhsT);
    attn_kernel<<<dim3(16, 64), 256, 0, stream>>>(A1, A2, khs, vhsT, rbf, mb, outp);
}

// Round 4
// 261.242 us; speedup vs baseline: 1.4850x; 1.4542x over previous
//
#include <hip/hip_runtime.h>

typedef short bf16x8 __attribute__((ext_vector_type(8)));
typedef float f32x4 __attribute__((ext_vector_type(4)));
typedef unsigned short u16;
typedef unsigned short u16x4 __attribute__((ext_vector_type(4)));
typedef unsigned short u16x8 __attribute__((ext_vector_type(8)));

#define NB 4
#define LEN 1024
#define DM 1024
#define NH 16
#define HD 64

__device__ __forceinline__ u16 f2bf(float f) {
    union { float f; unsigned u; } v; v.f = f;
    return (u16)((v.u + 0x7fffu + ((v.u >> 16) & 1u)) >> 16);
}

__device__ __forceinline__ f32x4 mfma16(bf16x8 a, bf16x8 b, f32x4 c) {
    return __builtin_amdgcn_mfma_f32_16x16x32_bf16(a, b, c, 0, 0, 0);
}

// async global->LDS, 16B per lane. LDS base must be wave-uniform (HW adds lane*16).
__device__ __forceinline__ void gload16(const void* g, void* l) {
    __builtin_amdgcn_global_load_lds(
        (const __attribute__((address_space(1))) unsigned int*)g,
        (__attribute__((address_space(3))) unsigned int*)l, 16, 0, 0);
}

// ---------------- cast fp32 -> bf16 (vectorized) ----------------
__global__ void cast_f32_bf16(const float* __restrict__ in, u16* __restrict__ out, int n4) {
    int i = blockIdx.x * blockDim.x + threadIdx.x;
    if (i < n4) {
        float4 v = ((const float4*)in)[i];
        u16x4 o;
        o[0] = f2bf(v.x); o[1] = f2bf(v.y); o[2] = f2bf(v.z); o[3] = f2bf(v.w);
        ((u16x4*)out)[i] = o;
    }
}

// ---------------- mask -> additive bias ----------------
__global__ void mask_bias(const int* __restrict__ mask, float* __restrict__ mb, int n) {
    int i = blockIdx.x * 256 + threadIdx.x;
    if (i < n) mb[i] = mask[i] ? 0.f : -3.0e38f;
}

// ---------------- transpose + cast weights: W[K][N] -> WT[N][K] bf16 ----------------
__global__ void transpose_cast(const float* __restrict__ W, u16* __restrict__ WT, int K, int N) {
    __shared__ float tile[32][33];
    int n0 = blockIdx.x * 32, k0 = blockIdx.y * 32;
    int tx = threadIdx.x, ty = threadIdx.y;
    #pragma unroll
    for (int j = 0; j < 4; j++) {
        int r = ty + j * 8;
        tile[r][tx] = W[(size_t)(k0 + r) * N + n0 + tx];
    }
    __syncthreads();
    #pragma unroll
    for (int j = 0; j < 4; j++) {
        int r = ty + j * 8;  // local n
        WT[(size_t)(n0 + r) * K + k0 + tx] = f2bf(tile[tx][r]);
    }
}

// ---------------- r = pos_embed @ Wr -> bf16, PRE-SWIZZLED rows, 2064 rows ----------------
// swizzle key = (row-1)&7 : LDS tiles start at j0 === 1 (mod 8)
__global__ void r_proj(const float* __restrict__ pos, const float* __restrict__ Wr,
                       u16* __restrict__ rbf) {
    int idx = blockIdx.x * 256 + threadIdx.x;  // 2064*64 = 132096
    if (idx >= 2064 * 64) return;
    int row = idx >> 6, col = idx & 63;
    float s = 0.f;
    if (row < 2048) {
        #pragma unroll
        for (int kk = 0; kk < 64; kk++) s += pos[row * 64 + kk] * Wr[kk * 64 + col];
    }
    const int csw = (((col >> 3) ^ ((row + 7) & 7)) << 3) | (col & 7);
    rbf[(row << 6) | csw] = f2bf(s);
}

// ---------------- projection GEMM: C = A(bf16 MxK) @ WT^T, fused epilogues ----------------
// mode 0: A1/A2 (linear).  mode 1: khs PRE-SWIZZLED (key k&7), vhs linear.
__global__ __launch_bounds__(256) void gemm_proj(
    const u16* __restrict__ Abf, const u16* __restrict__ BT,
    const float* __restrict__ rrb, const float* __restrict__ rwb,
    u16* __restrict__ out1, u16* __restrict__ out2, int mode)
{
    const int K = 1024;
    const int n0 = blockIdx.x * 64;
    const int m0 = blockIdx.y * 128;
    const int tid = threadIdx.x;
    const int w = tid >> 6, lane = tid & 63, g = lane >> 4, c = lane & 15;
    const int wr = m0 + w * 32;

    const f32x4 fzero = {0.f, 0.f, 0.f, 0.f};
    f32x4 acc[2][4];
    #pragma unroll
    for (int rt = 0; rt < 2; rt++) {
        #pragma unroll
        for (int ct = 0; ct < 4; ct++) acc[rt][ct] = fzero;
    }

    const u16* aptr0 = Abf + (size_t)(wr + c) * K + g * 8;
    const u16* aptr1 = Abf + (size_t)(wr + 16 + c) * K + g * 8;
    const u16* bptr0 = BT + (size_t)(n0 + c) * K + g * 8;
    const u16* bptr1 = BT + (size_t)(n0 + 16 + c) * K + g * 8;
    const u16* bptr2 = BT + (size_t)(n0 + 32 + c) * K + g * 8;
    const u16* bptr3 = BT + (size_t)(n0 + 48 + c) * K + g * 8;

    #pragma unroll 2
    for (int ks = 0; ks < 32; ks++) {
        const int off = ks * 32;
        bf16x8 a0 = *(const bf16x8*)(aptr0 + off);
        bf16x8 a1 = *(const bf16x8*)(aptr1 + off);
        bf16x8 b0 = *(const bf16x8*)(bptr0 + off);
        bf16x8 b1 = *(const bf16x8*)(bptr1 + off);
        bf16x8 b2 = *(const bf16x8*)(bptr2 + off);
        bf16x8 b3 = *(const bf16x8*)(bptr3 + off);
        acc[0][0] = mfma16(a0, b0, acc[0][0]);
        acc[1][0] = mfma16(a1, b0, acc[1][0]);
        acc[0][1] = mfma16(a0, b1, acc[0][1]);
        acc[1][1] = mfma16(a1, b1, acc[1][1]);
        acc[0][2] = mfma16(a0, b2, acc[0][2]);
        acc[1][2] = mfma16(a1, b2, acc[1][2]);
        acc[0][3] = mfma16(a0, b3, acc[0][3]);
        acc[1][3] = mfma16(a1, b3, acc[1][3]);
    }

    #pragma unroll
    for (int ct = 0; ct < 4; ct++) {
        const int n = n0 + ct * 16 + c;
        float b1v = 0.f, b2v = 0.f;
        if (mode == 0) { b1v = rrb[n]; b2v = rwb[n]; }
        #pragma unroll
        for (int rt = 0; rt < 2; rt++) {
            #pragma unroll
            for (int r = 0; r < 4; r++) {
                const int row = wr + rt * 16 + g * 4 + r;
                const int bb = row >> 10, l = row & 1023;
                const float v = acc[rt][ct][r];
                if (mode == 0) {
                    size_t idx = (((size_t)(bb * NH + (n >> 6))) * LEN + l) * HD + (n & 63);
                    out1[idx] = f2bf((v + b1v) * 0.125f);
                    out2[idx] = f2bf((v + b2v) * 0.125f);
                } else if (n < DM) {
                    const int d = n & 63;
                    const int dsw = (((d >> 3) ^ (l & 7)) << 3) | (d & 7);
                    size_t idx = (((size_t)(bb * NH + (n >> 6))) * LEN + l) * HD + dsw;
                    out1[idx] = f2bf(v);
                } else {
                    size_t idx = (((size_t)(bb * NH + ((n - DM) >> 6))) * LEN + l) * HD + (n & 63);
                    out2[idx] = f2bf(v);
                }
            }
        }
    }
}

// ---------------- vhs[b,h,l,d] -> vhsT[b,h,d,l] (linear) ----------------
__global__ void transpose_v(const u16* __restrict__ vhs, u16* __restrict__ vhsT) {
    __shared__ u16 tile[64][72];
    const int bhead = blockIdx.y;
    const int l0 = blockIdx.x * 64;
    const int tid = threadIdx.x;
    #pragma unroll
    for (int i = 0; i < 2; i++) {
        int idx = i * 256 + tid;
        int row = idx >> 3;
        int cg = (idx & 7) * 8;
        u16x8 v = *(const u16x8*)(vhs + ((size_t)bhead * LEN + l0 + row) * HD + cg);
        *(u16x8*)&tile[row][cg] = v;
    }
    __syncthreads();
    #pragma unroll
    for (int i = 0; i < 2; i++) {
        int idx = i * 256 + tid;
        int d = idx >> 3;
        int lg = (idx & 7) * 8;
        u16x8 o;
        #pragma unroll
        for (int j = 0; j < 8; j++) o[j] = tile[lg + j][d];
        *(u16x8*)(vhsT + ((size_t)bhead * HD + d) * LEN + l0 + lg) = o;
    }
}

// ---------------- fused rel-attention, v4: block-cooperative LDS staging ----------------
// grid (16, 64), 4 waves. q-block 64 (wave w: rows q0+16w..+15). KVBLK=32.
// K/R double-buffered per tile; V double-buffered per 64-key pair; 2-phase pipeline.
__global__ __launch_bounds__(256, 2) void attn_kernel(
    const u16* __restrict__ A1, const u16* __restrict__ A2,
    const u16* __restrict__ khs, const u16* __restrict__ vhsT,
    const u16* __restrict__ rbf, const float* __restrict__ mbias,
    float* __restrict__ outp)
{
    __shared__ u16 kbuf[2][32][64];        // 8 KB, rows swizzled by (k&7)
    __shared__ u16 rbuf[2][96][64];        // 24 KB, rows swizzled by (row_local&7)
    __shared__ u16 vbuf[2][8][64][8];      // 16 KB: [pairbuf][kgroup][d][8]
    __shared__ float biasl[1024];          // 4 KB
    __shared__ f32x4 gl[4][16][13];        // 13 KB, row stride 52 dwords
    __shared__ u16 pl[4][16][40];          // 5 KB

    const int bh = blockIdx.y;
    const int b = bh >> 4, h = bh & 15;
    const int tid = threadIdx.x;
    const int w = tid >> 6, lane = tid & 63, g = lane >> 4, c = lane & 15;
    const int q0 = blockIdx.x * 64, q0w = q0 + w * 16;
    const int lrow8 = lane >> 3, lcol = lane & 7;

    const u16* Kbase = khs + (size_t)bh * LEN * HD;
    const u16* Vbase = vhsT + (size_t)bh * HD * LEN;
    float* glw = (float*)&gl[w][0][0];

    // q-side fragments (B-operands), linear A1/A2
    const u16* A1p = A1 + ((size_t)bh * LEN + q0w) * HD;
    const u16* A2p = A2 + ((size_t)bh * LEN + q0w) * HD;
    bf16x8 a1f[2], a2f[2];
    #pragma unroll
    for (int kf = 0; kf < 2; kf++) {
        a1f[kf] = *(const bf16x8*)(A1p + c * HD + kf * 32 + g * 8);
        a2f[kf] = *(const bf16x8*)(A2p + c * HD + kf * 32 + g * 8);
    }

    // ---- prologue staging: bias + K/R tile 0 + V pair 0 ----
    gload16(mbias + b * LEN + w * 256 + lane * 4, &biasl[w * 256]);
    gload16(Kbase + (((size_t)(w * 8 + lrow8)) << 6) + (lcol << 3), &kbuf[0][w * 8][0]);
    {
        const int j00 = 1024 - q0 - 63;
        #pragma unroll
        for (int i = 0; i < 3; i++) {
            const int ci = w * 3 + i;
            gload16(rbf + (((size_t)(j00 + ci * 8 + lrow8)) << 6) + (lcol << 3), &rbuf[0][ci * 8][0]);
        }
    }
    #pragma unroll
    for (int i = 0; i < 2; i++) {
        const int ci = w * 2 + i;
        gload16(Vbase + ((size_t)lane << 10) + ci * 8, &vbuf[0][ci][0][0]);
    }
    __syncthreads();

    const f32x4 fzero = {0.f, 0.f, 0.f, 0.f};
    f32x4 oacc[4];
    #pragma unroll
    for (int dt = 0; dt < 4; dt++) oacc[dt] = fzero;
    float mrow = -3.0e38f, lrow = 0.f;

    for (int kt = 0; kt < 32; kt++) {
        const int cur = kt & 1, nb = cur ^ 1;
        const int pb = (kt >> 1) & 1, ph = kt & 1;
        const int c0 = kt * 32;

        // ---- prefetch next K/R tile ----
        if (kt < 31) {
            const int c0n = c0 + 32;
            gload16(Kbase + (((size_t)(c0n + w * 8 + lrow8)) << 6) + (lcol << 3), &kbuf[nb][w * 8][0]);
            const int j0n = 1024 + c0n - q0 - 63;
            #pragma unroll
            for (int i = 0; i < 3; i++) {
                const int ci = w * 3 + i;
                gload16(rbf + (((size_t)(j0n + ci * 8 + lrow8)) << 6) + (lcol << 3), &rbuf[nb][ci * 8][0]);
            }
        }
        // ---- prefetch next V pair (2 tiles ahead) ----
        if (!(kt & 1) && kt < 30) {
            const int p2 = (kt >> 1) + 1;
            #pragma unroll
            for (int i = 0; i < 2; i++) {
                const int ci = w * 2 + i;
                gload16(Vbase + ((size_t)lane << 10) + p2 * 64 + ci * 8, &vbuf[p2 & 1][ci][0][0]);
            }
        }

        // ---- K / R fragments from LDS (swizzled reads) ----
        bf16x8 Kf[2][2], Rf[3][2];
        #pragma unroll
        for (int ct = 0; ct < 2; ct++)
            #pragma unroll
            for (int kf = 0; kf < 2; kf++)
                Kf[ct][kf] = *(const bf16x8*)&kbuf[cur][16 * ct + c][((4 * kf + g) ^ (c & 7)) * 8];
        const int rb0 = 48 - 16 * w;
        #pragma unroll
        for (int gt = 0; gt < 3; gt++)
            #pragma unroll
            for (int kf = 0; kf < 2; kf++)
                Rf[gt][kf] = *(const bf16x8*)&rbuf[cur][rb0 + gt * 16 + c][((4 * kf + g) ^ (c & 7)) * 8];

        // ---- AC (S^T): lane q=c, k = 16ct+4g+r ----
        f32x4 s[2];
        s[0] = fzero; s[1] = fzero;
        s[0] = mfma16(Kf[0][0], a1f[0], s[0]);
        s[0] = mfma16(Kf[0][1], a1f[1], s[0]);
        s[1] = mfma16(Kf[1][0], a1f[0], s[1]);
        s[1] = mfma16(Kf[1][1], a1f[1], s[1]);

        // ---- band G[q=c][m], m = gt*16+4g+r ----
        #pragma unroll
        for (int gt = 0; gt < 3; gt++) {
            f32x4 ga = fzero;
            ga = mfma16(Rf[gt][0], a2f[0], ga);
            ga = mfma16(Rf[gt][1], a2f[1], ga);
            gl[w][c][gt * 4 + g] = ga;
        }

        // ---- gather band + bias: BD[c][k] = G[c][k+15-c] ----
        f32x4 bb0 = *(const f32x4*)&biasl[c0 + 4 * g];
        f32x4 bb1 = *(const f32x4*)&biasl[c0 + 16 + 4 * g];
        #pragma unroll
        for (int r = 0; r < 4; r++) {
            const int base = 51 * c + 4 * g + r + 15;
            s[0][r] += glw[base] + bb0[r];
            s[1][r] += glw[base + 16] + bb1[r];
        }

        // ---- online softmax ----
        float t = fmaxf(fmaxf(fmaxf(s[0][0], s[0][1]), fmaxf(s[0][2], s[0][3])),
                        fmaxf(fmaxf(s[1][0], s[1][1]), fmaxf(s[1][2], s[1][3])));
        t = fmaxf(t, __shfl_xor(t, 16));
        t = fmaxf(t, __shfl_xor(t, 32));
        const float mnew = fmaxf(mrow, t);
        const float alpha = __expf(mrow - mnew);
        mrow = mnew;
        float ps = 0.f;
        u16x4 pk0, pk1;
        #pragma unroll
        for (int r = 0; r < 4; r++) {
            float p0 = __expf(s[0][r] - mnew);
            float p1 = __expf(s[1][r] - mnew);
            ps += p0 + p1;
            pk0[r] = f2bf(p0);
            pk1[r] = f2bf(p1);
        }
        lrow = lrow * alpha + ps;
        #pragma unroll
        for (int dt = 0; dt < 4; dt++)
            #pragma unroll
            for (int r = 0; r < 4; r++) oacc[dt][r] *= alpha;

        // ---- P -> LDS, PV ----
        *(u16x4*)&pl[w][c][4 * g] = pk0;
        *(u16x4*)&pl[w][c][16 + 4 * g] = pk1;
        bf16x8 pbr = *(const bf16x8*)&pl[w][c][8 * g];
        #pragma unroll
        for (int dt = 0; dt < 4; dt++) {
            bf16x8 vf = *(const bf16x8*)&vbuf[pb][4 * ph + g][16 * dt + c][0];
            oacc[dt] = mfma16(vf, pbr, oacc[dt]);
        }

        __syncthreads();
    }

    // ---- epilogue ----
    float sum = lrow;
    sum += __shfl_xor(sum, 16);
    sum += __shfl_xor(sum, 32);
    const float inv = sum > 0.f ? 1.0f / sum : 0.f;
    const int l = q0w + c;
    float* op = outp + ((size_t)b * LEN + l) * DM + h * HD;
    #pragma unroll
    for (int dt = 0; dt < 4; dt++) {
        f32x4 o;
        #pragma unroll
        for (int r = 0; r < 4; r++) o[r] = oacc[dt][r] * inv;
        *(f32x4*)(op + dt * 16 + 4 * g) = o;
    }
}

extern "C" void kernel_launch(void* const* d_in, const int* in_sizes, int n_in,
                              void* d_out, int out_size, void* d_ws, size_t ws_size,
                              hipStream_t stream) {
    const float* q   = (const float*)d_in[0];
    const float* k   = (const float*)d_in[1];
    const int*   msk = (const int*)d_in[2];
    const float* pos = (const float*)d_in[3];
    const float* Wq  = (const float*)d_in[4];
    const float* Wkv = (const float*)d_in[5];
    const float* Wr  = (const float*)d_in[6];
    const float* rrb = (const float*)d_in[7];
    const float* rwb = (const float*)d_in[8];
    float* outp = (float*)d_out;
    char* ws = (char*)d_ws;

    u16* qbf  = (u16*)(ws + 0);              // 8 MB
    u16* kbf  = (u16*)(ws + 8388608);        // 8 MB
    u16* WqT  = (u16*)(ws + 16777216);       // 2 MB
    u16* WkvT = (u16*)(ws + 18874368);       // 4 MB
    u16* rbf  = (u16*)(ws + 23068672);       // 2064*64*2 (swizzled, rows>=2048 zero)
    u16* A1   = (u16*)(ws + 23332864);       // 8 MB
    u16* A2   = (u16*)(ws + 31721472);       // 8 MB
    u16* khs  = (u16*)(ws + 40110080);       // 8 MB (swizzled)
    u16* vhs  = (u16*)(ws + 48498688);       // 8 MB
    u16* vhsT = (u16*)(ws + 56887296);       // 8 MB
    float* mb = (float*)(ws + 65275904);     // 16 KB mask bias

    cast_f32_bf16<<<4096, 256, 0, stream>>>(q, qbf, 1048576);
    cast_f32_bf16<<<4096, 256, 0, stream>>>(k, kbf, 1048576);
    mask_bias<<<16, 256, 0, stream>>>(msk, mb, NB * LEN);
    transpose_cast<<<dim3(32, 32), dim3(32, 8), 0, stream>>>(Wq, WqT, 1024, 1024);
    transpose_cast<<<dim3(64, 32), dim3(32, 8), 0, stream>>>(Wkv, WkvT, 1024, 2048);
    r_proj<<<516, 256, 0, stream>>>(pos, Wr, rbf);
    gemm_proj<<<dim3(16, 32), 256, 0, stream>>>(qbf, WqT, rrb, rwb, A1, A2, 0);
    gemm_proj<<<dim3(32, 32), 256, 0, stream>>>(kbf, WkvT, nullptr, nullptr, khs, vhs, 1);
    transpose_v<<<dim3(16, 64), 256, 0, stream>>>(vhs, vhsT);
    attn_kernel<<<dim3(16, 64), 256, 0, stream>>>(A1, A2, khs, vhsT, rbf, mb, outp);
}

// Round 5
// 208.164 us; speedup vs baseline: 1.8637x; 1.2550x over previous
//
#include <hip/hip_runtime.h>

typedef short bf16x8 __attribute__((ext_vector_type(8)));
typedef float f32x4 __attribute__((ext_vector_type(4)));
typedef unsigned short u16;
typedef unsigned short u16x4 __attribute__((ext_vector_type(4)));
typedef unsigned short u16x8 __attribute__((ext_vector_type(8)));

#define NB 4
#define LEN 1024
#define DM 1024
#define NH 16
#define HD 64

__device__ __forceinline__ u16 f2bf(float f) {
    union { float f; unsigned u; } v; v.f = f;
    return (u16)((v.u + 0x7fffu + ((v.u >> 16) & 1u)) >> 16);
}

__device__ __forceinline__ f32x4 mfma16(bf16x8 a, bf16x8 b, f32x4 c) {
    return __builtin_amdgcn_mfma_f32_16x16x32_bf16(a, b, c, 0, 0, 0);
}

// async global->LDS, 16B per lane. LDS base must be wave-uniform (HW adds lane*16).
__device__ __forceinline__ void gload16(const void* g, void* l) {
    __builtin_amdgcn_global_load_lds(
        (const __attribute__((address_space(1))) unsigned int*)g,
        (__attribute__((address_space(3))) unsigned int*)l, 16, 0, 0);
}

// ---------------- cast fp32 -> bf16 (vectorized) ----------------
__global__ void cast_f32_bf16(const float* __restrict__ in, u16* __restrict__ out, int n4) {
    int i = blockIdx.x * blockDim.x + threadIdx.x;
    if (i < n4) {
        float4 v = ((const float4*)in)[i];
        u16x4 o;
        o[0] = f2bf(v.x); o[1] = f2bf(v.y); o[2] = f2bf(v.z); o[3] = f2bf(v.w);
        ((u16x4*)out)[i] = o;
    }
}

// ---------------- mask -> additive bias ----------------
__global__ void mask_bias(const int* __restrict__ mask, float* __restrict__ mb, int n) {
    int i = blockIdx.x * 256 + threadIdx.x;
    if (i < n) mb[i] = mask[i] ? 0.f : -3.0e38f;
}

// ---------------- transpose + cast weights: W[K][N] -> WT[N][K] bf16 ----------------
__global__ void transpose_cast(const float* __restrict__ W, u16* __restrict__ WT, int K, int N) {
    __shared__ float tile[32][33];
    int n0 = blockIdx.x * 32, k0 = blockIdx.y * 32;
    int tx = threadIdx.x, ty = threadIdx.y;
    #pragma unroll
    for (int j = 0; j < 4; j++) {
        int r = ty + j * 8;
        tile[r][tx] = W[(size_t)(k0 + r) * N + n0 + tx];
    }
    __syncthreads();
    #pragma unroll
    for (int j = 0; j < 4; j++) {
        int r = ty + j * 8;  // local n
        WT[(size_t)(n0 + r) * K + k0 + tx] = f2bf(tile[tx][r]);
    }
}

// ---------------- r = pos_embed @ Wr -> bf16, PRE-SWIZZLED rows, 2064 rows ----------------
// swizzle key = (row-1)&7 : LDS tiles start at j0 === 1 (mod 8)
__global__ void r_proj(const float* __restrict__ pos, const float* __restrict__ Wr,
                       u16* __restrict__ rbf) {
    int idx = blockIdx.x * 256 + threadIdx.x;  // 2064*64 = 132096
    if (idx >= 2064 * 64) return;
    int row = idx >> 6, col = idx & 63;
    float s = 0.f;
    if (row < 2048) {
        #pragma unroll
        for (int kk = 0; kk < 64; kk++) s += pos[row * 64 + kk] * Wr[kk * 64 + col];
    }
    const int csw = (((col >> 3) ^ ((row + 7) & 7)) << 3) | (col & 7);
    rbf[(row << 6) | csw] = f2bf(s);
}

// ---------------- LDS-staged 128x128 GEMM (m97 structure), fused epilogues ----------------
// C = A(bf16 MxK=1024) @ BT^T.  grid (N/128, M/128), 256 thr = 2x2 waves of 64x64.
// mode 0: out1 = (C+rrb)*0.125 -> A1, out2 = (C+rwb)*0.125 -> A2 (both [b,h,l,d])
// mode 1: n<1024 -> khs swizzled; n>=1024 -> vhsT[b,h,d,l] (fused V transpose)
__global__ __launch_bounds__(256) void gemm_tile(
    const u16* __restrict__ Abf, const u16* __restrict__ BT,
    const float* __restrict__ rrb, const float* __restrict__ rwb,
    u16* __restrict__ out1, u16* __restrict__ out2, int mode)
{
    __shared__ u16 as[2][128][32];   // 8 KB per buf, source pre-swizzled by (row&3)
    __shared__ u16 bs[2][128][32];

    const int n0 = blockIdx.x * 128;
    const int m0 = blockIdx.y * 128;
    const int tid = threadIdx.x;
    const int w = tid >> 6, lane = tid & 63, g = lane >> 4, c = lane & 15;
    const int wm = w >> 1, wn = w & 1;
    const int srow = lane >> 2, sj = lane & 3;   // staging: 4 lanes/row

    const f32x4 fzero = {0.f, 0.f, 0.f, 0.f};
    f32x4 acc[4][4];
    #pragma unroll
    for (int i = 0; i < 4; i++)
        #pragma unroll
        for (int j = 0; j < 4; j++) acc[i][j] = fzero;

    auto STAGE = [&](int buf, int ks) {
        const int k0 = ks * 32;
        #pragma unroll
        for (int i = 0; i < 2; i++) {
            const int rb = w * 32 + i * 16;          // 16 rows per gload
            const int rowA = rb + srow;
            gload16(Abf + (size_t)(m0 + rowA) * 1024 + k0 + ((sj ^ (rowA & 3)) << 3),
                    &as[buf][rb][0]);
            gload16(BT + (size_t)(n0 + rowA) * 1024 + k0 + ((sj ^ (rowA & 3)) << 3),
                    &bs[buf][rb][0]);
        }
    };

    STAGE(0, 0);
    __syncthreads();

    for (int ks = 0; ks < 32; ks++) {
        const int cur = ks & 1, nb = cur ^ 1;
        if (ks < 31) STAGE(nb, ks + 1);

        bf16x8 af[4], bfr[4];
        #pragma unroll
        for (int i = 0; i < 4; i++) {
            const int row = wm * 64 + i * 16 + c;
            af[i] = *(const bf16x8*)&as[cur][row][(g ^ (row & 3)) << 3];
        }
        #pragma unroll
        for (int j = 0; j < 4; j++) {
            const int row = wn * 64 + j * 16 + c;
            bfr[j] = *(const bf16x8*)&bs[cur][row][(g ^ (row & 3)) << 3];
        }
        #pragma unroll
        for (int i = 0; i < 4; i++)
            #pragma unroll
            for (int j = 0; j < 4; j++)
                acc[i][j] = mfma16(af[i], bfr[j], acc[i][j]);

        __syncthreads();
    }

    // ---- epilogue ----
    #pragma unroll
    for (int j = 0; j < 4; j++) {
        const int n = n0 + wn * 64 + j * 16 + c;
        float b1v = 0.f, b2v = 0.f;
        if (mode == 0) { b1v = rrb[n]; b2v = rwb[n]; }
        #pragma unroll
        for (int i = 0; i < 4; i++) {
            const int l0 = m0 + wm * 64 + i * 16 + 4 * g;
            if (mode == 1 && n >= DM) {
                // fused V transpose: vhsT[b, h, d, l], 4 consecutive l
                const int d = n & 63, hh = (n - DM) >> 6;
                const int bb = l0 >> 10, l = l0 & 1023;
                u16x4 o;
                #pragma unroll
                for (int r = 0; r < 4; r++) o[r] = f2bf(acc[i][j][r]);
                *(u16x4*)(out2 + (((size_t)(bb * NH + hh)) * HD + d) * LEN + l) = o;
            } else {
                #pragma unroll
                for (int r = 0; r < 4; r++) {
                    const int row = l0 + r;
                    const int bb = row >> 10, l = row & 1023;
                    const float v = acc[i][j][r];
                    if (mode == 0) {
                        size_t idx = (((size_t)(bb * NH + (n >> 6))) * LEN + l) * HD + (n & 63);
                        out1[idx] = f2bf((v + b1v) * 0.125f);
                        out2[idx] = f2bf((v + b2v) * 0.125f);
                    } else {
                        const int d = n & 63;
                        const int dsw = (((d >> 3) ^ (l & 7)) << 3) | (d & 7);
                        size_t idx = (((size_t)(bb * NH + (n >> 6))) * LEN + l) * HD + dsw;
                        out1[idx] = f2bf(v);
                    }
                }
            }
        }
    }
}

// ---------------- fused rel-attention, v5: lean LDS (50KB), 3 blocks/CU ----------------
// grid (16, 64), 4 waves. K/R block-staged + double-buffered; V + bias direct from L2.
__global__ __launch_bounds__(256, 3) void attn_kernel(
    const u16* __restrict__ A1, const u16* __restrict__ A2,
    const u16* __restrict__ khs, const u16* __restrict__ vhsT,
    const u16* __restrict__ rbf, const float* __restrict__ mbias,
    float* __restrict__ outp)
{
    __shared__ u16 kbuf[2][32][64];        // 8 KB, rows swizzled by (k&7)
    __shared__ u16 rbuf[2][96][64];        // 24 KB, rows swizzled by (row_local&7)
    __shared__ f32x4 gl[4][16][13];        // 13 KB, row stride 52 dwords
    __shared__ u16 pl[4][16][40];          // 5 KB

    const int bh = blockIdx.y;
    const int b = bh >> 4, h = bh & 15;
    const int tid = threadIdx.x;
    const int w = tid >> 6, lane = tid & 63, g = lane >> 4, c = lane & 15;
    const int q0 = blockIdx.x * 64, q0w = q0 + w * 16;
    const int lrow8 = lane >> 3, lcol = lane & 7;

    const u16* Kbase = khs + (size_t)bh * LEN * HD;
    const u16* Vp = vhsT + (size_t)bh * HD * LEN;
    const float* bp = mbias + b * LEN;
    float* glw = (float*)&gl[w][0][0];

    const u16* A1p = A1 + ((size_t)bh * LEN + q0w) * HD;
    const u16* A2p = A2 + ((size_t)bh * LEN + q0w) * HD;
    bf16x8 a1f[2], a2f[2];
    #pragma unroll
    for (int kf = 0; kf < 2; kf++) {
        a1f[kf] = *(const bf16x8*)(A1p + c * HD + kf * 32 + g * 8);
        a2f[kf] = *(const bf16x8*)(A2p + c * HD + kf * 32 + g * 8);
    }

    // ---- prologue staging: K/R tile 0 ----
    gload16(Kbase + (((size_t)(w * 8 + lrow8)) << 6) + (lcol << 3), &kbuf[0][w * 8][0]);
    {
        const int j00 = 1024 - q0 - 63;
        #pragma unroll
        for (int i = 0; i < 3; i++) {
            const int ci = w * 3 + i;
            gload16(rbf + (((size_t)(j00 + ci * 8 + lrow8)) << 6) + (lcol << 3), &rbuf[0][ci * 8][0]);
        }
    }
    __syncthreads();

    const f32x4 fzero = {0.f, 0.f, 0.f, 0.f};
    f32x4 oacc[4];
    #pragma unroll
    for (int dt = 0; dt < 4; dt++) oacc[dt] = fzero;
    float mrow = -3.0e38f, lrow = 0.f;

    for (int kt = 0; kt < 32; kt++) {
        const int cur = kt & 1, nb = cur ^ 1;
        const int c0 = kt * 32;

        // ---- prefetch next K/R tile into LDS ----
        if (kt < 31) {
            const int c0n = c0 + 32;
            gload16(Kbase + (((size_t)(c0n + w * 8 + lrow8)) << 6) + (lcol << 3), &kbuf[nb][w * 8][0]);
            const int j0n = 1024 + c0n - q0 - 63;
            #pragma unroll
            for (int i = 0; i < 3; i++) {
                const int ci = w * 3 + i;
                gload16(rbf + (((size_t)(j0n + ci * 8 + lrow8)) << 6) + (lcol << 3), &rbuf[nb][ci * 8][0]);
            }
        }

        // ---- V fragments + bias direct from global (L2-hot), issued early ----
        bf16x8 Vb[4];
        #pragma unroll
        for (int dt = 0; dt < 4; dt++)
            Vb[dt] = *(const bf16x8*)(Vp + (size_t)(dt * 16 + c) * LEN + c0 + g * 8);
        f32x4 bb0 = *(const f32x4*)(bp + c0 + 4 * g);
        f32x4 bb1 = *(const f32x4*)(bp + c0 + 16 + 4 * g);

        // ---- K / R fragments from LDS (swizzled reads) ----
        bf16x8 Kf[2][2], Rf[3][2];
        #pragma unroll
        for (int ct = 0; ct < 2; ct++)
            #pragma unroll
            for (int kf = 0; kf < 2; kf++)
                Kf[ct][kf] = *(const bf16x8*)&kbuf[cur][16 * ct + c][((4 * kf + g) ^ (c & 7)) * 8];
        const int rb0 = 48 - 16 * w;
        #pragma unroll
        for (int gt = 0; gt < 3; gt++)
            #pragma unroll
            for (int kf = 0; kf < 2; kf++)
                Rf[gt][kf] = *(const bf16x8*)&rbuf[cur][rb0 + gt * 16 + c][((4 * kf + g) ^ (c & 7)) * 8];

        // ---- AC (S^T): lane q=c, k = 16ct+4g+r ----
        f32x4 s[2];
        s[0] = fzero; s[1] = fzero;
        s[0] = mfma16(Kf[0][0], a1f[0], s[0]);
        s[0] = mfma16(Kf[0][1], a1f[1], s[0]);
        s[1] = mfma16(Kf[1][0], a1f[0], s[1]);
        s[1] = mfma16(Kf[1][1], a1f[1], s[1]);

        // ---- band G[q=c][m], m = gt*16+4g+r ----
        #pragma unroll
        for (int gt = 0; gt < 3; gt++) {
            f32x4 ga = fzero;
            ga = mfma16(Rf[gt][0], a2f[0], ga);
            ga = mfma16(Rf[gt][1], a2f[1], ga);
            gl[w][c][gt * 4 + g] = ga;
        }

        // ---- gather band + bias: BD[c][k] = G[c][k+15-c] ----
        #pragma unroll
        for (int r = 0; r < 4; r++) {
            const int base = 51 * c + 4 * g + r + 15;
            s[0][r] += glw[base] + bb0[r];
            s[1][r] += glw[base + 16] + bb1[r];
        }

        // ---- online softmax ----
        float t = fmaxf(fmaxf(fmaxf(s[0][0], s[0][1]), fmaxf(s[0][2], s[0][3])),
                        fmaxf(fmaxf(s[1][0], s[1][1]), fmaxf(s[1][2], s[1][3])));
        t = fmaxf(t, __shfl_xor(t, 16));
        t = fmaxf(t, __shfl_xor(t, 32));
        const float mnew = fmaxf(mrow, t);
        const float alpha = __expf(mrow - mnew);
        mrow = mnew;
        float ps = 0.f;
        u16x4 pk0, pk1;
        #pragma unroll
        for (int r = 0; r < 4; r++) {
            float p0 = __expf(s[0][r] - mnew);
            float p1 = __expf(s[1][r] - mnew);
            ps += p0 + p1;
            pk0[r] = f2bf(p0);
            pk1[r] = f2bf(p1);
        }
        lrow = lrow * alpha + ps;
        #pragma unroll
        for (int dt = 0; dt < 4; dt++)
            #pragma unroll
            for (int r = 0; r < 4; r++) oacc[dt][r] *= alpha;

        // ---- P -> LDS, PV ----
        *(u16x4*)&pl[w][c][4 * g] = pk0;
        *(u16x4*)&pl[w][c][16 + 4 * g] = pk1;
        bf16x8 pbr = *(const bf16x8*)&pl[w][c][8 * g];
        #pragma unroll
        for (int dt = 0; dt < 4; dt++)
            oacc[dt] = mfma16(Vb[dt], pbr, oacc[dt]);

        __syncthreads();
    }

    // ---- epilogue ----
    float sum = lrow;
    sum += __shfl_xor(sum, 16);
    sum += __shfl_xor(sum, 32);
    const float inv = sum > 0.f ? 1.0f / sum : 0.f;
    const int l = q0w + c;
    float* op = outp + ((size_t)b * LEN + l) * DM + h * HD;
    #pragma unroll
    for (int dt = 0; dt < 4; dt++) {
        f32x4 o;
        #pragma unroll
        for (int r = 0; r < 4; r++) o[r] = oacc[dt][r] * inv;
        *(f32x4*)(op + dt * 16 + 4 * g) = o;
    }
}

extern "C" void kernel_launch(void* const* d_in, const int* in_sizes, int n_in,
                              void* d_out, int out_size, void* d_ws, size_t ws_size,
                              hipStream_t stream) {
    const float* q   = (const float*)d_in[0];
    const float* k   = (const float*)d_in[1];
    const int*   msk = (const int*)d_in[2];
    const float* pos = (const float*)d_in[3];
    const float* Wq  = (const float*)d_in[4];
    const float* Wkv = (const float*)d_in[5];
    const float* Wr  = (const float*)d_in[6];
    const float* rrb = (const float*)d_in[7];
    const float* rwb = (const float*)d_in[8];
    float* outp = (float*)d_out;
    char* ws = (char*)d_ws;

    u16* qbf  = (u16*)(ws + 0);              // 8 MB
    u16* kbf  = (u16*)(ws + 8388608);        // 8 MB
    u16* WqT  = (u16*)(ws + 16777216);       // 2 MB
    u16* WkvT = (u16*)(ws + 18874368);       // 4 MB
    u16* rbf  = (u16*)(ws + 23068672);       // 2064*64*2 (swizzled, rows>=2048 zero)
    u16* A1   = (u16*)(ws + 23332864);       // 8 MB
    u16* A2   = (u16*)(ws + 31721472);       // 8 MB
    u16* khs  = (u16*)(ws + 40110080);       // 8 MB (swizzled)
    u16* vhsT = (u16*)(ws + 48498688);       // 8 MB
    float* mb = (float*)(ws + 56887296);     // 16 KB mask bias

    cast_f32_bf16<<<4096, 256, 0, stream>>>(q, qbf, 1048576);
    cast_f32_bf16<<<4096, 256, 0, stream>>>(k, kbf, 1048576);
    mask_bias<<<16, 256, 0, stream>>>(msk, mb, NB * LEN);
    transpose_cast<<<dim3(32, 32), dim3(32, 8), 0, stream>>>(Wq, WqT, 1024, 1024);
    transpose_cast<<<dim3(64, 32), dim3(32, 8), 0, stream>>>(Wkv, WkvT, 1024, 2048);
    r_proj<<<516, 256, 0, stream>>>(pos, Wr, rbf);
    gemm_tile<<<dim3(8, 32), 256, 0, stream>>>(qbf, WqT, rrb, rwb, A1, A2, 0);
    gemm_tile<<<dim3(16, 32), 256, 0, stream>>>(kbf, WkvT, nullptr, nullptr, khs, vhsT, 1);
    attn_kernel<<<dim3(16, 64), 256, 0, stream>>>(A1, A2, khs, vhsT, rbf, mb, outp);
}

// Round 6
// 182.770 us; speedup vs baseline: 2.1226x; 1.1389x over previous
//
#include <hip/hip_runtime.h>

typedef short bf16x8 __attribute__((ext_vector_type(8)));
typedef float f32x4 __attribute__((ext_vector_type(4)));
typedef unsigned short u16;
typedef unsigned short u16x4 __attribute__((ext_vector_type(4)));
typedef unsigned short u16x8 __attribute__((ext_vector_type(8)));

#define NB 4
#define LEN 1024
#define DM 1024
#define NH 16
#define HD 64

__device__ __forceinline__ u16 f2bf(float f) {
    union { float f; unsigned u; } v; v.f = f;
    return (u16)((v.u + 0x7fffu + ((v.u >> 16) & 1u)) >> 16);
}

__device__ __forceinline__ float bf2f(u16 x) {
    union { float f; unsigned u; } v; v.u = ((unsigned)x) << 16;
    return v.f;
}

__device__ __forceinline__ f32x4 mfma16(bf16x8 a, bf16x8 b, f32x4 c) {
    return __builtin_amdgcn_mfma_f32_16x16x32_bf16(a, b, c, 0, 0, 0);
}

// async global->LDS, 16B per lane. LDS base must be wave-uniform (HW adds lane*16).
__device__ __forceinline__ void gload16(const void* g, void* l) {
    __builtin_amdgcn_global_load_lds(
        (const __attribute__((address_space(1))) unsigned int*)g,
        (__attribute__((address_space(3))) unsigned int*)l, 16, 0, 0);
}

// ---------------- cast fp32 -> bf16 (vectorized) ----------------
__global__ void cast_f32_bf16(const float* __restrict__ in, u16* __restrict__ out, int n4) {
    int i = blockIdx.x * blockDim.x + threadIdx.x;
    if (i < n4) {
        float4 v = ((const float4*)in)[i];
        u16x4 o;
        o[0] = f2bf(v.x); o[1] = f2bf(v.y); o[2] = f2bf(v.z); o[3] = f2bf(v.w);
        ((u16x4*)out)[i] = o;
    }
}

// ---------------- mask -> additive bias ----------------
__global__ void mask_bias(const int* __restrict__ mask, float* __restrict__ mb, int n) {
    int i = blockIdx.x * 256 + threadIdx.x;
    if (i < n) mb[i] = mask[i] ? 0.f : -3.0e38f;
}

// ---------------- transpose + cast weights: W[K][N] -> WT[N][K] bf16 ----------------
__global__ void transpose_cast(const float* __restrict__ W, u16* __restrict__ WT, int K, int N) {
    __shared__ float tile[32][33];
    int n0 = blockIdx.x * 32, k0 = blockIdx.y * 32;
    int tx = threadIdx.x, ty = threadIdx.y;
    #pragma unroll
    for (int j = 0; j < 4; j++) {
        int r = ty + j * 8;
        tile[r][tx] = W[(size_t)(k0 + r) * N + n0 + tx];
    }
    __syncthreads();
    #pragma unroll
    for (int j = 0; j < 4; j++) {
        int r = ty + j * 8;  // local n
        WT[(size_t)(n0 + r) * K + k0 + tx] = f2bf(tile[tx][r]);
    }
}

// ---------------- r = pos_embed @ Wr -> bf16, PRE-SWIZZLED rows (key = row&7) ----------------
__global__ void r_proj(const float* __restrict__ pos, const float* __restrict__ Wr,
                       u16* __restrict__ rbf) {
    int idx = blockIdx.x * 256 + threadIdx.x;  // 2064*64 = 132096
    if (idx >= 2064 * 64) return;
    int row = idx >> 6, col = idx & 63;
    float s = 0.f;
    if (row < 2048) {
        #pragma unroll
        for (int kk = 0; kk < 64; kk++) s += pos[row * 64 + kk] * Wr[kk * 64 + col];
    }
    const int csw = (((col >> 3) ^ (row & 7)) << 3) | (col & 7);
    rbf[(row << 6) | csw] = f2bf(s);
}

// ---------------- LDS-staged 128x128 GEMM (m97 structure), fused epilogues ----------------
__global__ __launch_bounds__(256) void gemm_tile(
    const u16* __restrict__ Abf, const u16* __restrict__ BT,
    const float* __restrict__ rrb, const float* __restrict__ rwb,
    u16* __restrict__ out1, u16* __restrict__ out2, int mode)
{
    __shared__ u16 as[2][128][32];
    __shared__ u16 bs[2][128][32];

    const int n0 = blockIdx.x * 128;
    const int m0 = blockIdx.y * 128;
    const int tid = threadIdx.x;
    const int w = tid >> 6, lane = tid & 63, g = lane >> 4, c = lane & 15;
    const int wm = w >> 1, wn = w & 1;
    const int srow = lane >> 2, sj = lane & 3;

    const f32x4 fzero = {0.f, 0.f, 0.f, 0.f};
    f32x4 acc[4][4];
    #pragma unroll
    for (int i = 0; i < 4; i++)
        #pragma unroll
        for (int j = 0; j < 4; j++) acc[i][j] = fzero;

    auto STAGE = [&](int buf, int ks) {
        const int k0 = ks * 32;
        #pragma unroll
        for (int i = 0; i < 2; i++) {
            const int rb = w * 32 + i * 16;
            const int rowA = rb + srow;
            gload16(Abf + (size_t)(m0 + rowA) * 1024 + k0 + ((sj ^ (rowA & 3)) << 3),
                    &as[buf][rb][0]);
            gload16(BT + (size_t)(n0 + rowA) * 1024 + k0 + ((sj ^ (rowA & 3)) << 3),
                    &bs[buf][rb][0]);
        }
    };

    STAGE(0, 0);
    __syncthreads();

    for (int ks = 0; ks < 32; ks++) {
        const int cur = ks & 1, nb = cur ^ 1;
        if (ks < 31) STAGE(nb, ks + 1);

        bf16x8 af[4], bfr[4];
        #pragma unroll
        for (int i = 0; i < 4; i++) {
            const int row = wm * 64 + i * 16 + c;
            af[i] = *(const bf16x8*)&as[cur][row][(g ^ (row & 3)) << 3];
        }
        #pragma unroll
        for (int j = 0; j < 4; j++) {
            const int row = wn * 64 + j * 16 + c;
            bfr[j] = *(const bf16x8*)&bs[cur][row][(g ^ (row & 3)) << 3];
        }
        #pragma unroll
        for (int i = 0; i < 4; i++)
            #pragma unroll
            for (int j = 0; j < 4; j++)
                acc[i][j] = mfma16(af[i], bfr[j], acc[i][j]);

        __syncthreads();
    }

    #pragma unroll
    for (int j = 0; j < 4; j++) {
        const int n = n0 + wn * 64 + j * 16 + c;
        float b1v = 0.f, b2v = 0.f;
        if (mode == 0) { b1v = rrb[n]; b2v = rwb[n]; }
        #pragma unroll
        for (int i = 0; i < 4; i++) {
            const int l0 = m0 + wm * 64 + i * 16 + 4 * g;
            if (mode == 1 && n >= DM) {
                const int d = n & 63, hh = (n - DM) >> 6;
                const int bb = l0 >> 10, l = l0 & 1023;
                u16x4 o;
                #pragma unroll
                for (int r = 0; r < 4; r++) o[r] = f2bf(acc[i][j][r]);
                *(u16x4*)(out2 + (((size_t)(bb * NH + hh)) * HD + d) * LEN + l) = o;
            } else {
                #pragma unroll
                for (int r = 0; r < 4; r++) {
                    const int row = l0 + r;
                    const int bb = row >> 10, l = row & 1023;
                    const float v = acc[i][j][r];
                    if (mode == 0) {
                        size_t idx = (((size_t)(bb * NH + (n >> 6))) * LEN + l) * HD + (n & 63);
                        out1[idx] = f2bf((v + b1v) * 0.125f);
                        out2[idx] = f2bf((v + b2v) * 0.125f);
                    } else {
                        const int d = n & 63;
                        const int dsw = (((d >> 3) ^ (l & 7)) << 3) | (d & 7);
                        size_t idx = (((size_t)(bb * NH + (n >> 6))) * LEN + l) * HD + dsw;
                        out1[idx] = f2bf(v);
                    }
                }
            }
        }
    }
}

// ---------------- fused rel-attention, v6: 32 q-rows/wave, rolling R ring ----------------
// grid (64, 8): x = b*16+h (XCD locality on K/V), y = q-chunk of 128.
// 4 waves; wave w owns q rows [q0+32w, q0+32w+32) as two 16-row S^T subtiles. KVBLK=32.
__global__ __launch_bounds__(256, 2) void attn_kernel(
    const u16* __restrict__ A1, const u16* __restrict__ A2,
    const u16* __restrict__ khs, const u16* __restrict__ vhsT,
    const u16* __restrict__ rbf, const float* __restrict__ mbias,
    float* __restrict__ outp)
{
    __shared__ u16 kbuf[2][32][64];      // 8 KB, rows swizzled by key k&7
    __shared__ u16 rbuf[192][64];        // 24 KB rolling ring (slot = j mod 192), key j&7
    __shared__ u16 vbuf[2][4][64][8];    // 8 KB: [buf][kgroup][d][8 keys]
    __shared__ float biasl[1024];        // 4 KB
    __shared__ u16 gl[4][32][72];        // 18 KB bf16 band scores, row stride 72
    __shared__ u16 pl[4][32][40];        // 10 KB P tiles

    const int bh = blockIdx.x;
    const int b = bh >> 4, h = bh & 15;
    const int tid = threadIdx.x;
    const int w = tid >> 6, lane = tid & 63, g = lane >> 4, c = lane & 15;
    const int q0 = blockIdx.y * 128, q0w = q0 + w * 32;
    const int lrow8 = lane >> 3, lcol = lane & 7;
    const int kkey = (c + 1) & 7;

    const u16* Kbase = khs + (size_t)bh * LEN * HD;
    const u16* Vp = vhsT + (size_t)bh * HD * LEN;
    u16* glw = &gl[w][0][0];
    u16* plw = &pl[w][0][0];

    // q-side fragments (B-operands): subtile qs: row = q0w + qs*16 + c
    const u16* A1p = A1 + ((size_t)bh * LEN + q0w) * HD;
    const u16* A2p = A2 + ((size_t)bh * LEN + q0w) * HD;
    bf16x8 a1f[2][2], a2f[2][2];
    #pragma unroll
    for (int qs = 0; qs < 2; qs++)
        #pragma unroll
        for (int kf = 0; kf < 2; kf++) {
            a1f[qs][kf] = *(const bf16x8*)(A1p + (qs * 16 + c) * HD + kf * 32 + g * 8);
            a2f[qs][kf] = *(const bf16x8*)(A2p + (qs * 16 + c) * HD + kf * 32 + g * 8);
        }

    // ---- prologue staging ----
    gload16(mbias + b * LEN + w * 256 + lane * 4, &biasl[w * 256]);
    gload16(Kbase + (((size_t)(w * 8 + lrow8)) << 6) + (lcol << 3), &kbuf[0][w * 8][0]);
    gload16(Vp + ((size_t)lane << 10) + w * 8, &vbuf[0][w][0][0]);
    const int js0 = LEN - q0 - 128;                  // ring fill start (== 0 mod 8)
    #pragma unroll
    for (int i = 0; i < 5; i++) {
        const int jg = js0 + (w + 4 * i) * 8;        // 20 groups of 8 rows
        gload16(rbf + (((size_t)(jg + lrow8)) << 6) + (lcol << 3), &rbuf[jg % 192][0]);
    }
    __syncthreads();

    int psl = (js0 + 160) % 192;                     // ring slot of next prefetch group 0
    int bsl = (LEN - q0w - 31) % 192;                // ring slot of this wave's band base

    const f32x4 fzero = {0.f, 0.f, 0.f, 0.f};
    f32x4 oacc[2][4];
    #pragma unroll
    for (int qs = 0; qs < 2; qs++)
        #pragma unroll
        for (int dt = 0; dt < 4; dt++) oacc[qs][dt] = fzero;
    float mrow[2] = {-3.0e38f, -3.0e38f}, lrow[2] = {0.f, 0.f};

    for (int kt = 0; kt < 32; kt++) {
        const int cur = kt & 1, nb = cur ^ 1;
        const int c0 = kt * 32;

        // ---- prefetch next tile (K, V, 32 new R ring rows) ----
        if (kt < 31) {
            const int c0n = c0 + 32;
            gload16(Kbase + (((size_t)(c0n + w * 8 + lrow8)) << 6) + (lcol << 3), &kbuf[nb][w * 8][0]);
            gload16(Vp + ((size_t)lane << 10) + c0n + w * 8, &vbuf[nb][w][0][0]);
            const int pg = js0 + 160 + 32 * kt + 8 * w;
            int ps = psl + 8 * w; if (ps >= 192) ps -= 192;
            gload16(rbf + (((size_t)(pg + lrow8)) << 6) + (lcol << 3), &rbuf[ps][0]);
        }

        // ---- K fragments ----
        bf16x8 Kf[2][2];
        #pragma unroll
        for (int ct = 0; ct < 2; ct++)
            #pragma unroll
            for (int kf = 0; kf < 2; kf++)
                Kf[ct][kf] = *(const bf16x8*)&kbuf[cur][16 * ct + c][((4 * kf + g) ^ (c & 7)) * 8];

        // ---- R fragments from ring ----
        bf16x8 Rf[4][2];
        #pragma unroll
        for (int mt = 0; mt < 4; mt++) {
            int t = bsl + mt * 16 + c; if (t >= 192) t -= 192;
            #pragma unroll
            for (int kf = 0; kf < 2; kf++)
                Rf[mt][kf] = *(const bf16x8*)&rbuf[t][((4 * kf + g) ^ kkey) * 8];
        }

        // ---- AC (S^T): subtile qs, lane q = c, k = 16ct+4g+r ----
        f32x4 s[2][2];
        #pragma unroll
        for (int qs = 0; qs < 2; qs++)
            #pragma unroll
            for (int ct = 0; ct < 2; ct++) {
                f32x4 a = fzero;
                a = mfma16(Kf[ct][0], a1f[qs][0], a);
                a = mfma16(Kf[ct][1], a1f[qs][1], a);
                s[qs][ct] = a;
            }

        // ---- band G (bf16): qs0 rows c (mt 1..3), qs1 rows c+16 (mt 0..2) ----
        #pragma unroll
        for (int mt = 1; mt < 4; mt++) {
            f32x4 ga = fzero;
            ga = mfma16(Rf[mt][0], a2f[0][0], ga);
            ga = mfma16(Rf[mt][1], a2f[0][1], ga);
            u16x4 o;
            #pragma unroll
            for (int r = 0; r < 4; r++) o[r] = f2bf(ga[r]);
            *(u16x4*)&glw[c * 72 + mt * 16 + 4 * g] = o;
        }
        #pragma unroll
        for (int mt = 0; mt < 3; mt++) {
            f32x4 ga = fzero;
            ga = mfma16(Rf[mt][0], a2f[1][0], ga);
            ga = mfma16(Rf[mt][1], a2f[1][1], ga);
            u16x4 o;
            #pragma unroll
            for (int r = 0; r < 4; r++) o[r] = f2bf(ga[r]);
            *(u16x4*)&glw[(c + 16) * 72 + mt * 16 + 4 * g] = o;
        }

        // ---- gather band + bias: BD[q][k] = G[q][k + 31 - qlocal] ----
        f32x4 bb0 = *(const f32x4*)&biasl[c0 + 4 * g];
        f32x4 bb1 = *(const f32x4*)&biasl[c0 + 16 + 4 * g];
        #pragma unroll
        for (int r = 0; r < 4; r++) {
            const int m0_ = 4 * g + r + 31 - c;              // qs0, ct0
            s[0][0][r] += bf2f(glw[c * 72 + m0_]) + bb0[r];
            s[0][1][r] += bf2f(glw[c * 72 + m0_ + 16]) + bb1[r];
            const int m1_ = 4 * g + r + 15 - c;              // qs1, ct0
            s[1][0][r] += bf2f(glw[(c + 16) * 72 + m1_]) + bb0[r];
            s[1][1][r] += bf2f(glw[(c + 16) * 72 + m1_ + 16]) + bb1[r];
        }

        // ---- online softmax + P + PV per subtile ----
        bf16x8 Vb[4];
        #pragma unroll
        for (int dt = 0; dt < 4; dt++)
            Vb[dt] = *(const bf16x8*)&vbuf[cur][g][16 * dt + c][0];

        #pragma unroll
        for (int qs = 0; qs < 2; qs++) {
            float t = fmaxf(fmaxf(fmaxf(s[qs][0][0], s[qs][0][1]), fmaxf(s[qs][0][2], s[qs][0][3])),
                            fmaxf(fmaxf(s[qs][1][0], s[qs][1][1]), fmaxf(s[qs][1][2], s[qs][1][3])));
            t = fmaxf(t, __shfl_xor(t, 16));
            t = fmaxf(t, __shfl_xor(t, 32));
            const float mnew = fmaxf(mrow[qs], t);
            const float alpha = __expf(mrow[qs] - mnew);
            mrow[qs] = mnew;
            float ps = 0.f;
            u16x4 pk0, pk1;
            #pragma unroll
            for (int r = 0; r < 4; r++) {
                float p0 = __expf(s[qs][0][r] - mnew);
                float p1 = __expf(s[qs][1][r] - mnew);
                ps += p0 + p1;
                pk0[r] = f2bf(p0);
                pk1[r] = f2bf(p1);
            }
            lrow[qs] = lrow[qs] * alpha + ps;
            #pragma unroll
            for (int dt = 0; dt < 4; dt++)
                #pragma unroll
                for (int r = 0; r < 4; r++) oacc[qs][dt][r] *= alpha;
            *(u16x4*)&plw[(qs * 16 + c) * 40 + 4 * g] = pk0;
            *(u16x4*)&plw[(qs * 16 + c) * 40 + 16 + 4 * g] = pk1;
            bf16x8 pbr = *(const bf16x8*)&plw[(qs * 16 + c) * 40 + 8 * g];
            #pragma unroll
            for (int dt = 0; dt < 4; dt++)
                oacc[qs][dt] = mfma16(Vb[dt], pbr, oacc[qs][dt]);
        }

        psl += 32; if (psl >= 192) psl -= 192;
        bsl += 32; if (bsl >= 192) bsl -= 192;
        __syncthreads();
    }

    // ---- epilogue ----
    #pragma unroll
    for (int qs = 0; qs < 2; qs++) {
        float sum = lrow[qs];
        sum += __shfl_xor(sum, 16);
        sum += __shfl_xor(sum, 32);
        const float inv = sum > 0.f ? 1.0f / sum : 0.f;
        const int l = q0w + qs * 16 + c;
        float* op = outp + ((size_t)b * LEN + l) * DM + h * HD;
        #pragma unroll
        for (int dt = 0; dt < 4; dt++) {
            f32x4 o;
            #pragma unroll
            for (int r = 0; r < 4; r++) o[r] = oacc[qs][dt][r] * inv;
            *(f32x4*)(op + dt * 16 + 4 * g) = o;
        }
    }
}

extern "C" void kernel_launch(void* const* d_in, const int* in_sizes, int n_in,
                              void* d_out, int out_size, void* d_ws, size_t ws_size,
                              hipStream_t stream) {
    const float* q   = (const float*)d_in[0];
    const float* k   = (const float*)d_in[1];
    const int*   msk = (const int*)d_in[2];
    const float* pos = (const float*)d_in[3];
    const float* Wq  = (const float*)d_in[4];
    const float* Wkv = (const float*)d_in[5];
    const float* Wr  = (const float*)d_in[6];
    const float* rrb = (const float*)d_in[7];
    const float* rwb = (const float*)d_in[8];
    float* outp = (float*)d_out;
    char* ws = (char*)d_ws;

    u16* qbf  = (u16*)(ws + 0);              // 8 MB
    u16* kbf  = (u16*)(ws + 8388608);        // 8 MB
    u16* WqT  = (u16*)(ws + 16777216);       // 2 MB
    u16* WkvT = (u16*)(ws + 18874368);       // 4 MB
    u16* rbf  = (u16*)(ws + 23068672);       // 2064*64*2 (swizzled key row&7)
    u16* A1   = (u16*)(ws + 23332864);       // 8 MB
    u16* A2   = (u16*)(ws + 31721472);       // 8 MB
    u16* khs  = (u16*)(ws + 40110080);       // 8 MB (swizzled key l&7)
    u16* vhsT = (u16*)(ws + 48498688);       // 8 MB
    float* mb = (float*)(ws + 56887296);     // 16 KB mask bias

    cast_f32_bf16<<<4096, 256, 0, stream>>>(q, qbf, 1048576);
    cast_f32_bf16<<<4096, 256, 0, stream>>>(k, kbf, 1048576);
    mask_bias<<<16, 256, 0, stream>>>(msk, mb, NB * LEN);
    transpose_cast<<<dim3(32, 32), dim3(32, 8), 0, stream>>>(Wq, WqT, 1024, 1024);
    transpose_cast<<<dim3(64, 32), dim3(32, 8), 0, stream>>>(Wkv, WkvT, 1024, 2048);
    r_proj<<<516, 256, 0, stream>>>(pos, Wr, rbf);
    gemm_tile<<<dim3(8, 32), 256, 0, stream>>>(qbf, WqT, rrb, rwb, A1, A2, 0);
    gemm_tile<<<dim3(16, 32), 256, 0, stream>>>(kbf, WkvT, nullptr, nullptr, khs, vhsT, 1);
    attn_kernel<<<dim3(64, 8), 256, 0, stream>>>(A1, A2, khs, vhsT, rbf, mb, outp);
}

// Round 7
// 124.703 us; speedup vs baseline: 3.1111x; 1.4656x over previous
//
#include <hip/hip_runtime.h>

typedef short bf16x8 __attribute__((ext_vector_type(8)));
typedef float f32x4 __attribute__((ext_vector_type(4)));
typedef unsigned short u16;
typedef unsigned short u16x4 __attribute__((ext_vector_type(4)));
typedef unsigned short u16x8 __attribute__((ext_vector_type(8)));

#define NB 4
#define LEN 1024
#define DM 1024
#define NH 16
#define HD 64

// 0.125 (1/sqrt(hd)) * log2(e): projections are emitted in exp2-domain
#define QSCALE 0.18033688011112043f

__device__ __forceinline__ u16 f2bf(float f) {
    union { float f; unsigned u; } v; v.f = f;
    return (u16)((v.u + 0x7fffu + ((v.u >> 16) & 1u)) >> 16);
}

__device__ __forceinline__ float exp2f_fast(float x) {
    float r; asm("v_exp_f32 %0, %1" : "=v"(r) : "v"(x)); return r;
}

__device__ __forceinline__ unsigned cvt_pk_bf16(float a, float b) {
    unsigned r; asm("v_cvt_pk_bf16_f32 %0, %1, %2" : "=v"(r) : "v"(a), "v"(b)); return r;
}

__device__ __forceinline__ f32x4 mfma16(bf16x8 a, bf16x8 b, f32x4 c) {
    return __builtin_amdgcn_mfma_f32_16x16x32_bf16(a, b, c, 0, 0, 0);
}

// async global->LDS, 16B per lane. LDS base must be wave-uniform (HW adds lane*16).
__device__ __forceinline__ void gload16(const void* g, void* l) {
    __builtin_amdgcn_global_load_lds(
        (const __attribute__((address_space(1))) unsigned int*)g,
        (__attribute__((address_space(3))) unsigned int*)l, 16, 0, 0);
}

// ---------------- cast q,k -> bf16 + mask -> bias, one launch ----------------
__global__ void cast_all(const float* __restrict__ q, const float* __restrict__ k,
                         const int* __restrict__ msk,
                         u16* __restrict__ qbf, u16* __restrict__ kbf,
                         float* __restrict__ mb) {
    int idx = blockIdx.x * 256 + threadIdx.x;
    if (idx < 1048576) {
        float4 v = ((const float4*)q)[idx];
        u16x4 o;
        o[0] = f2bf(v.x); o[1] = f2bf(v.y); o[2] = f2bf(v.z); o[3] = f2bf(v.w);
        ((u16x4*)qbf)[idx] = o;
    } else if (idx < 2097152) {
        int i = idx - 1048576;
        float4 v = ((const float4*)k)[i];
        u16x4 o;
        o[0] = f2bf(v.x); o[1] = f2bf(v.y); o[2] = f2bf(v.z); o[3] = f2bf(v.w);
        ((u16x4*)kbf)[i] = o;
    } else {
        int i = idx - 2097152;
        if (i < NB * LEN) mb[i] = msk[i] ? 0.f : -3.0e38f;
    }
}

// ---------------- transpose + cast both weights: W[K][N] -> WT[N][K] bf16 ----------------
__global__ void transWT(const float* __restrict__ Wq, const float* __restrict__ Wkv,
                        u16* __restrict__ WqT, u16* __restrict__ WkvT) {
    __shared__ float tile[32][33];
    const bool isQ = blockIdx.x < 32;
    const float* W = isQ ? Wq : Wkv;
    u16* WT = isQ ? WqT : WkvT;
    const int N = isQ ? 1024 : 2048;
    const int n0 = (isQ ? blockIdx.x : blockIdx.x - 32) * 32;
    const int k0 = blockIdx.y * 32;
    int tx = threadIdx.x, ty = threadIdx.y;
    #pragma unroll
    for (int j = 0; j < 4; j++) {
        int r = ty + j * 8;
        tile[r][tx] = W[(size_t)(k0 + r) * N + n0 + tx];
    }
    __syncthreads();
    #pragma unroll
    for (int j = 0; j < 4; j++) {
        int r = ty + j * 8;
        WT[(size_t)(n0 + r) * 1024 + k0 + tx] = f2bf(tile[tx][r]);
    }
}

// ---------------- r = pos_embed @ Wr -> bf16, PRE-SWIZZLED rows (key = row&7) ----------------
__global__ void r_proj(const float* __restrict__ pos, const float* __restrict__ Wr,
                       u16* __restrict__ rbf) {
    int idx = blockIdx.x * 256 + threadIdx.x;  // 2064*64
    if (idx >= 2064 * 64) return;
    int row = idx >> 6, col = idx & 63;
    float s = 0.f;
    if (row < 2048) {
        #pragma unroll
        for (int kk = 0; kk < 64; kk++) s += pos[row * 64 + kk] * Wr[kk * 64 + col];
    }
    const int csw = (((col >> 3) ^ (row & 7)) << 3) | (col & 7);
    rbf[(row << 6) | csw] = f2bf(s);
}

// ---------------- unified 128x128 projection GEMM (Q + KV in one launch) ----------------
// grid (24, 32): bx<8 -> Q path (A1/A2, exp2-scaled); else KV path (khs swizzled / vhsT).
__global__ __launch_bounds__(256) void gemm_all(
    const u16* __restrict__ qbf, const u16* __restrict__ kbf,
    const u16* __restrict__ WqT, const u16* __restrict__ WkvT,
    const float* __restrict__ rrb, const float* __restrict__ rwb,
    u16* __restrict__ A1, u16* __restrict__ A2,
    u16* __restrict__ khs, u16* __restrict__ vhsT)
{
    __shared__ u16 as[2][128][32];
    __shared__ u16 bs[2][128][32];

    const int bx = blockIdx.x;
    const bool isQ = bx < 8;
    const u16* Abf = isQ ? qbf : kbf;
    const u16* BT  = isQ ? WqT : WkvT;
    const int n0 = (isQ ? bx : bx - 8) * 128;
    const int m0 = blockIdx.y * 128;
    const int tid = threadIdx.x;
    const int w = tid >> 6, lane = tid & 63, g = lane >> 4, c = lane & 15;
    const int wm = w >> 1, wn = w & 1;
    const int srow = lane >> 2, sj = lane & 3;

    const f32x4 fzero = {0.f, 0.f, 0.f, 0.f};
    f32x4 acc[4][4];
    #pragma unroll
    for (int i = 0; i < 4; i++)
        #pragma unroll
        for (int j = 0; j < 4; j++) acc[i][j] = fzero;

    auto STAGE = [&](int buf, int ks) {
        const int k0 = ks * 32;
        #pragma unroll
        for (int i = 0; i < 2; i++) {
            const int rb = w * 32 + i * 16;
            const int rowA = rb + srow;
            gload16(Abf + (size_t)(m0 + rowA) * 1024 + k0 + ((sj ^ (rowA & 3)) << 3),
                    &as[buf][rb][0]);
            gload16(BT + (size_t)(n0 + rowA) * 1024 + k0 + ((sj ^ (rowA & 3)) << 3),
                    &bs[buf][rb][0]);
        }
    };

    STAGE(0, 0);
    __syncthreads();

    for (int ks = 0; ks < 32; ks++) {
        const int cur = ks & 1, nb = cur ^ 1;
        if (ks < 31) STAGE(nb, ks + 1);

        bf16x8 af[4], bfr[4];
        #pragma unroll
        for (int i = 0; i < 4; i++) {
            const int row = wm * 64 + i * 16 + c;
            af[i] = *(const bf16x8*)&as[cur][row][(g ^ (row & 3)) << 3];
        }
        #pragma unroll
        for (int j = 0; j < 4; j++) {
            const int row = wn * 64 + j * 16 + c;
            bfr[j] = *(const bf16x8*)&bs[cur][row][(g ^ (row & 3)) << 3];
        }
        #pragma unroll
        for (int i = 0; i < 4; i++)
            #pragma unroll
            for (int j = 0; j < 4; j++)
                acc[i][j] = mfma16(af[i], bfr[j], acc[i][j]);

        __syncthreads();
    }

    #pragma unroll
    for (int j = 0; j < 4; j++) {
        const int n = n0 + wn * 64 + j * 16 + c;
        float b1v = 0.f, b2v = 0.f;
        if (isQ) { b1v = rrb[n]; b2v = rwb[n]; }
        #pragma unroll
        for (int i = 0; i < 4; i++) {
            const int l0 = m0 + wm * 64 + i * 16 + 4 * g;
            if (!isQ && n >= DM) {
                const int d = n & 63, hh = (n - DM) >> 6;
                const int bb = l0 >> 10, l = l0 & 1023;
                u16x4 o;
                #pragma unroll
                for (int r = 0; r < 4; r++) o[r] = f2bf(acc[i][j][r]);
                *(u16x4*)(vhsT + (((size_t)(bb * NH + hh)) * HD + d) * LEN + l) = o;
            } else {
                #pragma unroll
                for (int r = 0; r < 4; r++) {
                    const int row = l0 + r;
                    const int bb = row >> 10, l = row & 1023;
                    const float v = acc[i][j][r];
                    if (isQ) {
                        size_t idx = (((size_t)(bb * NH + (n >> 6))) * LEN + l) * HD + (n & 63);
                        A1[idx] = f2bf((v + b1v) * QSCALE);
                        A2[idx] = f2bf((v + b2v) * QSCALE);
                    } else {
                        const int d = n & 63;
                        const int dsw = (((d >> 3) ^ (l & 7)) << 3) | (d & 7);
                        size_t idx = (((size_t)(bb * NH + (n >> 6))) * LEN + l) * HD + dsw;
                        khs[idx] = f2bf(v);
                    }
                }
            }
        }
    }
}

// ---------------- fused rel-attention, v7: f32 G + read2 gathers + exp2 + defer-max ----------------
// grid (64, 8): x = b*16+h (XCD locality on K/V), y = q-chunk of 128.
// 4 waves; wave w owns q rows [q0+32w, +32) as two 16-row S^T subtiles. KVBLK=32.
__global__ __launch_bounds__(256, 2) void attn_kernel(
    const u16* __restrict__ A1, const u16* __restrict__ A2,
    const u16* __restrict__ khs, const u16* __restrict__ vhsT,
    const u16* __restrict__ rbf, const float* __restrict__ mbias,
    float* __restrict__ outp)
{
    __shared__ u16 kbuf[2][32][64];      // 8 KB, rows swizzled by key k&7
    __shared__ u16 rbuf[192][64];        // 24 KB rolling ring (slot = j mod 192), key j&7
    __shared__ u16 vbuf[2][4][64][8];    // 8 KB: [buf][kgroup][d][8 keys]
    __shared__ float biasl[1024];        // 4 KB
    __shared__ float gl[4][2][16][52];   // 26 KB f32 band scores, stride 52 (208B, 16B-aligned)
    __shared__ u16 pl[4][32][40];        // 10 KB P tiles
    // total 81920 B exactly -> 2 blocks/CU

    const int bh = blockIdx.x;
    const int b = bh >> 4, h = bh & 15;
    const int tid = threadIdx.x;
    const int w = tid >> 6, lane = tid & 63, g = lane >> 4, c = lane & 15;
    const int q0 = blockIdx.y * 128, q0w = q0 + w * 32;
    const int lrow8 = lane >> 3, lcol = lane & 7;
    const int kkey = (c + 1) & 7;

    const u16* Kbase = khs + (size_t)bh * LEN * HD;
    const u16* Vp = vhsT + (size_t)bh * HD * LEN;
    u16* plw = &pl[w][0][0];

    const u16* A1p = A1 + ((size_t)bh * LEN + q0w) * HD;
    const u16* A2p = A2 + ((size_t)bh * LEN + q0w) * HD;
    bf16x8 a1f[2][2], a2f[2][2];
    #pragma unroll
    for (int qs = 0; qs < 2; qs++)
        #pragma unroll
        for (int kf = 0; kf < 2; kf++) {
            a1f[qs][kf] = *(const bf16x8*)(A1p + (qs * 16 + c) * HD + kf * 32 + g * 8);
            a2f[qs][kf] = *(const bf16x8*)(A2p + (qs * 16 + c) * HD + kf * 32 + g * 8);
        }

    // ---- prologue staging ----
    gload16(mbias + b * LEN + w * 256 + lane * 4, &biasl[w * 256]);
    gload16(Kbase + (((size_t)(w * 8 + lrow8)) << 6) + (lcol << 3), &kbuf[0][w * 8][0]);
    gload16(Vp + ((size_t)lane << 10) + w * 8, &vbuf[0][w][0][0]);
    const int js0 = LEN - q0 - 128;                  // ring fill start (== 0 mod 8)
    #pragma unroll
    for (int i = 0; i < 5; i++) {
        const int jg = js0 + (w + 4 * i) * 8;
        gload16(rbf + (((size_t)(jg + lrow8)) << 6) + (lcol << 3), &rbuf[jg % 192][0]);
    }
    __syncthreads();

    int psl = (js0 + 160) % 192;
    int bsl = (LEN - q0w - 31) % 192;

    const f32x4 fzero = {0.f, 0.f, 0.f, 0.f};
    f32x4 oacc[2][4];
    #pragma unroll
    for (int qs = 0; qs < 2; qs++)
        #pragma unroll
        for (int dt = 0; dt < 4; dt++) oacc[qs][dt] = fzero;
    float mrow[2] = {-3.0e38f, -3.0e38f}, lrow[2] = {0.f, 0.f};

    for (int kt = 0; kt < 32; kt++) {
        const int cur = kt & 1, nb = cur ^ 1;
        const int c0 = kt * 32;

        // ---- prefetch next tile (K, V, 32 new R ring rows) ----
        if (kt < 31) {
            const int c0n = c0 + 32;
            gload16(Kbase + (((size_t)(c0n + w * 8 + lrow8)) << 6) + (lcol << 3), &kbuf[nb][w * 8][0]);
            gload16(Vp + ((size_t)lane << 10) + c0n + w * 8, &vbuf[nb][w][0][0]);
            const int pg = js0 + 160 + 32 * kt + 8 * w;
            int ps = psl + 8 * w; if (ps >= 192) ps -= 192;
            gload16(rbf + (((size_t)(pg + lrow8)) << 6) + (lcol << 3), &rbuf[ps][0]);
        }

        // ---- K fragments ----
        bf16x8 Kf[2][2];
        #pragma unroll
        for (int ct = 0; ct < 2; ct++)
            #pragma unroll
            for (int kf = 0; kf < 2; kf++)
                Kf[ct][kf] = *(const bf16x8*)&kbuf[cur][16 * ct + c][((4 * kf + g) ^ (c & 7)) * 8];

        // ---- R fragments from ring ----
        bf16x8 Rf[4][2];
        #pragma unroll
        for (int mt = 0; mt < 4; mt++) {
            int t = bsl + mt * 16 + c; if (t >= 192) t -= 192;
            #pragma unroll
            for (int kf = 0; kf < 2; kf++)
                Rf[mt][kf] = *(const bf16x8*)&rbuf[t][((4 * kf + g) ^ kkey) * 8];
        }

        // ---- AC (S^T): subtile qs, lane q = c, k = 16ct+4g+r ----
        f32x4 s[2][2];
        #pragma unroll
        for (int qs = 0; qs < 2; qs++)
            #pragma unroll
            for (int ct = 0; ct < 2; ct++) {
                f32x4 a = fzero;
                a = mfma16(Kf[ct][0], a1f[qs][0], a);
                a = mfma16(Kf[ct][1], a1f[qs][1], a);
                s[qs][ct] = a;
            }

        // ---- band G (f32): qs0 uses mt 1..3, qs1 uses mt 0..2; b128 stores ----
        #pragma unroll
        for (int mt = 1; mt < 4; mt++) {
            f32x4 ga = fzero;
            ga = mfma16(Rf[mt][0], a2f[0][0], ga);
            ga = mfma16(Rf[mt][1], a2f[0][1], ga);
            *(f32x4*)&gl[w][0][c][(mt - 1) * 16 + 4 * g] = ga;
        }
        #pragma unroll
        for (int mt = 0; mt < 3; mt++) {
            f32x4 ga = fzero;
            ga = mfma16(Rf[mt][0], a2f[1][0], ga);
            ga = mfma16(Rf[mt][1], a2f[1][1], ga);
            *(f32x4*)&gl[w][1][c][mt * 16 + 4 * g] = ga;
        }

        // ---- gather band + bias: unified gidx = k + 15 - c (per-subtile-local) ----
        const float* glq0 = &gl[w][0][c][0];
        const float* glq1 = &gl[w][1][c][0];
        f32x4 bb0 = *(const f32x4*)&biasl[c0 + 4 * g];
        f32x4 bb1 = *(const f32x4*)&biasl[c0 + 16 + 4 * g];
        #pragma unroll
        for (int r = 0; r < 4; r++) {
            const int gidx = 4 * g + r + 15 - c;
            s[0][0][r] += glq0[gidx] + bb0[r];
            s[0][1][r] += glq0[gidx + 16] + bb1[r];
            s[1][0][r] += glq1[gidx] + bb0[r];
            s[1][1][r] += glq1[gidx + 16] + bb1[r];
        }

        // ---- online softmax (exp2 domain, defer-max) + P + PV per subtile ----
        bf16x8 Vb[4];
        #pragma unroll
        for (int dt = 0; dt < 4; dt++)
            Vb[dt] = *(const bf16x8*)&vbuf[cur][g][16 * dt + c][0];

        #pragma unroll
        for (int qs = 0; qs < 2; qs++) {
            float t = fmaxf(fmaxf(fmaxf(s[qs][0][0], s[qs][0][1]), fmaxf(s[qs][0][2], s[qs][0][3])),
                            fmaxf(fmaxf(s[qs][1][0], s[qs][1][1]), fmaxf(s[qs][1][2], s[qs][1][3])));
            t = fmaxf(t, __shfl_xor(t, 16));
            t = fmaxf(t, __shfl_xor(t, 32));
            if (!__all(t <= mrow[qs] + 8.f)) {
                const float mnew = fmaxf(mrow[qs], t);
                const float alpha = exp2f_fast(mrow[qs] - mnew);
                mrow[qs] = mnew;
                lrow[qs] *= alpha;
                #pragma unroll
                for (int dt = 0; dt < 4; dt++)
                    #pragma unroll
                    for (int r = 0; r < 4; r++) oacc[qs][dt][r] *= alpha;
            }
            const float mref = mrow[qs];
            float p[8];
            float ps = 0.f;
            #pragma unroll
            for (int r = 0; r < 4; r++) {
                p[r] = exp2f_fast(s[qs][0][r] - mref);
                p[4 + r] = exp2f_fast(s[qs][1][r] - mref);
                ps += p[r] + p[4 + r];
            }
            lrow[qs] += ps;
            const unsigned d0 = cvt_pk_bf16(p[0], p[1]);
            const unsigned d1 = cvt_pk_bf16(p[2], p[3]);
            const unsigned d2 = cvt_pk_bf16(p[4], p[5]);
            const unsigned d3 = cvt_pk_bf16(p[6], p[7]);
            const int prow = (qs * 16 + c) * 40;
            *(uint2*)&plw[prow + 4 * g] = make_uint2(d0, d1);
            *(uint2*)&plw[prow + 16 + 4 * g] = make_uint2(d2, d3);
            bf16x8 pbr = *(const bf16x8*)&plw[prow + 8 * g];
            #pragma unroll
            for (int dt = 0; dt < 4; dt++)
                oacc[qs][dt] = mfma16(Vb[dt], pbr, oacc[qs][dt]);
        }

        psl += 32; if (psl >= 192) psl -= 192;
        bsl += 32; if (bsl >= 192) bsl -= 192;
        __syncthreads();
    }

    // ---- epilogue ----
    #pragma unroll
    for (int qs = 0; qs < 2; qs++) {
        float sum = lrow[qs];
        sum += __shfl_xor(sum, 16);
        sum += __shfl_xor(sum, 32);
        const float inv = sum > 0.f ? 1.0f / sum : 0.f;
        const int l = q0w + qs * 16 + c;
        float* op = outp + ((size_t)b * LEN + l) * DM + h * HD;
        #pragma unroll
        for (int dt = 0; dt < 4; dt++) {
            f32x4 o;
            #pragma unroll
            for (int r = 0; r < 4; r++) o[r] = oacc[qs][dt][r] * inv;
            *(f32x4*)(op + dt * 16 + 4 * g) = o;
        }
    }
}

extern "C" void kernel_launch(void* const* d_in, const int* in_sizes, int n_in,
                              void* d_out, int out_size, void* d_ws, size_t ws_size,
                              hipStream_t stream) {
    const float* q   = (const float*)d_in[0];
    const float* k   = (const float*)d_in[1];
    const int*   msk = (const int*)d_in[2];
    const float* pos = (const float*)d_in[3];
    const float* Wq  = (const float*)d_in[4];
    const float* Wkv = (const float*)d_in[5];
    const float* Wr  = (const float*)d_in[6];
    const float* rrb = (const float*)d_in[7];
    const float* rwb = (const float*)d_in[8];
    float* outp = (float*)d_out;
    char* ws = (char*)d_ws;

    u16* qbf  = (u16*)(ws + 0);              // 8 MB
    u16* kbf  = (u16*)(ws + 8388608);        // 8 MB
    u16* WqT  = (u16*)(ws + 16777216);       // 2 MB
    u16* WkvT = (u16*)(ws + 18874368);       // 4 MB
    u16* rbf  = (u16*)(ws + 23068672);       // 2064*64*2 (swizzled key row&7)
    u16* A1   = (u16*)(ws + 23332864);       // 8 MB (exp2-scaled)
    u16* A2   = (u16*)(ws + 31721472);       // 8 MB (exp2-scaled)
    u16* khs  = (u16*)(ws + 40110080);       // 8 MB (swizzled key l&7)
    u16* vhsT = (u16*)(ws + 48498688);       // 8 MB
    float* mb = (float*)(ws + 56887296);     // 16 KB mask bias

    cast_all<<<8208, 256, 0, stream>>>(q, k, msk, qbf, kbf, mb);
    transWT<<<dim3(96, 32), dim3(32, 8), 0, stream>>>(Wq, Wkv, WqT, WkvT);
    r_proj<<<516, 256, 0, stream>>>(pos, Wr, rbf);
    gemm_all<<<dim3(24, 32), 256, 0, stream>>>(qbf, kbf, WqT, WkvT, rrb, rwb, A1, A2, khs, vhsT);
    attn_kernel<<<dim3(64, 8), 256, 0, stream>>>(A1, A2, khs, vhsT, rbf, mb, outp);
}